// Round 1
// baseline (5760.803 us; speedup 1.0000x reference)
//
#include <hip/hip_runtime.h>

typedef unsigned short u16;
typedef unsigned int   u32;
typedef short s8v __attribute__((ext_vector_type(8)));
typedef short s4v __attribute__((ext_vector_type(4)));
typedef float f4v __attribute__((ext_vector_type(4)));

// Problem constants
#define TT 32
#define BB 32
#define LL 128
#define FF 512
#define HH 1024
#define G4 4096
#define SCALE_ 0.08838834764831845f   // 1/sqrt(128)

// ---------- helpers ----------
__device__ __forceinline__ u16 f2bf(float f){
  u32 u = __float_as_uint(f);
  u32 r = u + 0x7fffu + ((u >> 16) & 1u);   // RNE
  return (u16)(r >> 16);
}
__device__ __forceinline__ float bf2f(u16 s){ return __uint_as_float(((u32)s) << 16); }
__device__ __forceinline__ float sigf(float x){ return 1.f / (1.f + __expf(-x)); }

// MFMA via inline asm (sidesteps builtin signature differences across ROCm versions)
__device__ __forceinline__ void mfma16(f4v& d, s8v a, s8v b){
  asm("v_mfma_f32_16x16x32_bf16 %0, %1, %2, %0" : "+v"(d) : "v"(a), "v"(b));
}

typedef __attribute__((address_space(3))) u32 as3u32;
typedef __attribute__((address_space(1))) u32 as1u32;
__device__ __forceinline__ void glds16(const u16* g, u16* l){
  __builtin_amdgcn_global_load_lds((const as1u32*)g, (as3u32*)l, 16, 0, 0);
}

// device-scope grid barrier: all blocks co-resident (grid=64 <= 256 CUs)
__device__ __forceinline__ void gbar(u32* cnt, u32 nblk, u32& epoch){
  __syncthreads();
  ++epoch;
  if (threadIdx.x == 0){
    __threadfence();                       // release: wb L2 -> MALL (cross-XCD)
    atomicAdd(cnt, 1u);
    u32 target = epoch * nblk;
    while (__hip_atomic_load(cnt, __ATOMIC_RELAXED, __HIP_MEMORY_SCOPE_AGENT) < target){
      __builtin_amdgcn_s_sleep(4);
    }
    __threadfence();                       // acquire: inv L1/L2
  }
  __syncthreads();
}

// ---------- prep kernels ----------
__global__ void k_convert(const float* __restrict__ src, u16* __restrict__ dst, int n){
  int i = blockIdx.x * blockDim.x + threadIdx.x;
  int st = gridDim.x * blockDim.x;
  for (; i < n; i += st) dst[i] = f2bf(src[i]);
}
__global__ void k_split_w1(const float* __restrict__ w1, u16* __restrict__ w1c, u16* __restrict__ w1o){
  int i = blockIdx.x * blockDim.x + threadIdx.x;
  int st = gridDim.x * blockDim.x;
  const int n = G4 * (FF + HH);
  for (; i < n; i += st){
    int j = i / 1536, k = i - j * 1536;
    u16 v = f2bf(w1[i]);
    if (k < HH) w1c[j * HH + k] = v;
    else        w1o[j * FF + (k - HH)] = v;
  }
}
__global__ void k_addb(const float* __restrict__ a, const float* __restrict__ b,
                       float* __restrict__ o, int n){
  int i = blockIdx.x * blockDim.x + threadIdx.x;
  int st = gridDim.x * blockDim.x;
  for (; i < n; i += st) o[i] = a[i] + b[i];
}
// demonstration[0] (B,L,F) fp32 -> (L*B, F) bf16
__global__ void k_demo_t(const float* __restrict__ d, u16* __restrict__ o){
  const int n = LL * BB * FF;
  int i = blockIdx.x * blockDim.x + threadIdx.x;
  int st = gridDim.x * blockDim.x;
  for (; i < n; i += st){
    int f = i & 511;
    int row = i >> 9;          // l*32+b
    int l = row >> 5, b = row & 31;
    o[i] = f2bf(d[(size_t)b * (LL * FF) + l * FF + f]);
  }
}

// ---------- generic GEMM: C(MxN) bf16 = A(MxK)bf16 * B(NxK)^T bf16 + bias ----------
// 128x128 tile, BK=64, 4 waves (2x2), global_load_lds staging. M,N %128==0, K %64==0.
template<int RELU>
__global__ void __launch_bounds__(256) k_gemm_bt(const u16* __restrict__ A, const u16* __restrict__ B,
        const float* __restrict__ bias, u16* __restrict__ C, int M, int N, int K)
{
  __shared__ u16 As[128 * 64];
  __shared__ u16 Bs[128 * 64];
  const int tid = threadIdx.x;
  const int lane = tid & 63, wave = tid >> 6;
  const int m0 = blockIdx.x * 128, n0 = blockIdx.y * 128;
  const int wm = wave >> 1, wn = wave & 1;
  const int lr = lane & 15, lk = (lane >> 4) * 8;
  f4v acc[4][4];
  #pragma unroll
  for (int i = 0; i < 4; i++)
    #pragma unroll
    for (int j = 0; j < 4; j++) acc[i][j] = f4v{0.f, 0.f, 0.f, 0.f};

  for (int kt = 0; kt < K; kt += 64){
    #pragma unroll
    for (int i = 0; i < 4; i++){
      int c = tid + i * 256;
      int row = c >> 3, cc = (c & 7) * 8;
      glds16(A + (size_t)(m0 + row) * K + kt + cc, &As[c * 8]);
      glds16(B + (size_t)(n0 + row) * K + kt + cc, &Bs[c * 8]);
    }
    __syncthreads();   // drains vmcnt -> LDS ready
    #pragma unroll
    for (int ks = 0; ks < 2; ++ks){
      int ko = ks * 32 + lk;
      s8v av[4], bv[4];
      #pragma unroll
      for (int m = 0; m < 4; m++) av[m] = *(const s8v*)&As[(wm * 64 + m * 16 + lr) * 64 + ko];
      #pragma unroll
      for (int n = 0; n < 4; n++) bv[n] = *(const s8v*)&Bs[(wn * 64 + n * 16 + lr) * 64 + ko];
      #pragma unroll
      for (int m = 0; m < 4; m++)
        #pragma unroll
        for (int n = 0; n < 4; n++) mfma16(acc[m][n], av[m], bv[n]);
    }
    __syncthreads();
  }
  const int r0 = (lane >> 4) * 4;
  #pragma unroll
  for (int m = 0; m < 4; m++){
    #pragma unroll
    for (int n = 0; n < 4; n++){
      int col = n0 + wn * 64 + n * 16 + lr;
      float bc = bias[col];
      #pragma unroll
      for (int r = 0; r < 4; r++){
        int row = m0 + wm * 64 + m * 16 + r0 + r;
        float v = acc[m][n][r] + bc;
        if (RELU) v = fmaxf(v, 0.f);
        C[(size_t)row * N + col] = f2bf(v);
      }
    }
  }
}

// ---------- encoder: 128 sequential LSTM steps, persistent, 1 grid barrier/step ----------
// 64 blocks x 256 thr. Block owns 16 h-cols; wave g computes gate-group g (i/f/g/o).
__global__ void __launch_bounds__(256) k_encoder(const u16* __restrict__ Whh, const u16* __restrict__ Xih,
      u16* __restrict__ hbuf /*2 x 32*1024 bf16*/, u16* __restrict__ denc, u32* bar)
{
  const int nb = blockIdx.x, tid = threadIdx.x;
  const int lane = tid & 63, g = tid >> 6;
  const int jc = nb * 16;
  const int lr = lane & 15, lk = (lane >> 4) * 8;
  const int eb = tid >> 4, ejj = tid & 15;  // this thread's elementwise elems: (eb,ejj),(eb+16,ejj)
  __shared__ float gx[4][32][16];

  for (int i = tid; i < 512; i += 256){     // zero h buf0 (own cols)
    int b = i >> 4, jj = i & 15;
    hbuf[b * HH + jc + jj] = 0;
  }
  float cr0 = 0.f, cr1 = 0.f;
  u32 epoch = 0;
  gbar(bar, 64, epoch);

  const u16* Wb = Whh + (size_t)(g * HH + jc + lr) * HH + lk;
  for (int l = 0; l < LL; ++l){
    const u16* hb = hbuf + (l & 1) * (BB * HH);
    const u16* A0 = hb + lr * HH + lk;
    const u16* A1 = A0 + 16 * HH;
    f4v a0 = {0.f,0.f,0.f,0.f}, a1 = {0.f,0.f,0.f,0.f};
    #pragma unroll 8
    for (int ks = 0; ks < 32; ++ks){
      s8v va0 = *(const s8v*)(A0 + ks * 32);
      s8v va1 = *(const s8v*)(A1 + ks * 32);
      s8v vb  = *(const s8v*)(Wb + ks * 32);
      mfma16(a0, va0, vb);
      mfma16(a1, va1, vb);
    }
    {
      int rb = (lane >> 4) * 4;
      #pragma unroll
      for (int r = 0; r < 4; r++){ gx[g][rb + r][lr] = a0[r]; gx[g][16 + rb + r][lr] = a1[r]; }
    }
    __syncthreads();
    u16* ho = hbuf + ((l + 1) & 1) * (BB * HH);
    {
      const u16* xr = Xih + ((size_t)(l * BB + eb)) * G4 + jc + ejj;
      float gi = gx[0][eb][ejj] + bf2f(xr[0]);
      float gf = gx[1][eb][ejj] + bf2f(xr[1024]);
      float gg = gx[2][eb][ejj] + bf2f(xr[2048]);
      float go = gx[3][eb][ejj] + bf2f(xr[3072]);
      cr0 = sigf(gf) * cr0 + sigf(gi) * tanhf(gg);
      float h = sigf(go) * tanhf(cr0);
      u16 hv = f2bf(h);
      ho[eb * HH + jc + ejj] = hv;
      denc[((size_t)(l * BB + eb)) * HH + jc + ejj] = hv;
    }
    {
      int b2 = eb + 16;
      const u16* xr = Xih + ((size_t)(l * BB + b2)) * G4 + jc + ejj;
      float gi = gx[0][b2][ejj] + bf2f(xr[0]);
      float gf = gx[1][b2][ejj] + bf2f(xr[1024]);
      float gg = gx[2][b2][ejj] + bf2f(xr[2048]);
      float go = gx[3][b2][ejj] + bf2f(xr[3072]);
      cr1 = sigf(gf) * cr1 + sigf(gi) * tanhf(gg);
      float h = sigf(go) * tanhf(cr1);
      u16 hv = f2bf(h);
      ho[b2 * HH + jc + ejj] = hv;
      denc[((size_t)(l * BB + b2)) * HH + jc + ejj] = hv;
    }
    gbar(bar, 64, epoch);
  }
}

// ---------- decoder: 32 steps x 4 phases ----------
__global__ void __launch_bounds__(256) k_decoder(
    const u16* __restrict__ aproj, const u16* __restrict__ denc, const u16* __restrict__ obsp,
    const u16* __restrict__ W1c, const u16* __restrict__ W2w, const u16* __restrict__ WihL,
    const u16* __restrict__ WhhL, const float* __restrict__ blstm, const float* __restrict__ b2,
    const float* __restrict__ h0, const float* __restrict__ c0, const int* __restrict__ lens,
    float* __restrict__ hf, u16* __restrict__ hbuf, u16* __restrict__ ctxb,
    u16* __restrict__ mb, u16* __restrict__ xb, float* __restrict__ out, u32* bar)
{
  const int nb = blockIdx.x, tid = threadIdx.x;
  const int lane = tid & 63, w = tid >> 6;
  const int jc = nb * 16;
  const int lr = lane & 15, lk = (lane >> 4) * 8;
  const int eb = tid >> 4, ejj = tid & 15;
  __shared__ float gx[4][32][16];
  __shared__ float ssc[128];
  __shared__ float swt[128];

  float cr0, cr1;
  {
    float hv0 = h0[eb * HH + jc + ejj];
    float hv1 = h0[(eb + 16) * HH + jc + ejj];
    hf[eb * HH + jc + ejj] = hv0;
    hf[(eb + 16) * HH + jc + ejj] = hv1;
    hbuf[eb * HH + jc + ejj] = f2bf(hv0);
    hbuf[(eb + 16) * HH + jc + ejj] = f2bf(hv1);
    cr0 = c0[eb * HH + jc + ejj];
    cr1 = c0[(eb + 16) * HH + jc + ejj];
  }
  u32 epoch = 0;
  gbar(bar, 64, epoch);

  for (int t = 0; t < TT; ++t){
    // ---- Phase A: scores -> softmax -> ctx (blocks 0..31, one per batch row) ----
    if (nb < BB){
      const int b = nb;
      const int len = lens[b];
      for (int i = 0; i < 32; ++i){
        int l = w * 32 + i;
        const u16* ap = aproj + ((size_t)(l * BB + b)) * HH + lane * 16;
        const float* hp = hf + b * HH + lane * 16;
        s8v v0 = *(const s8v*)ap;
        s8v v1 = *(const s8v*)(ap + 8);
        float s = 0.f;
        #pragma unroll
        for (int k = 0; k < 8; k++) s += bf2f((u16)v0[k]) * hp[k];
        #pragma unroll
        for (int k = 0; k < 8; k++) s += bf2f((u16)v1[k]) * hp[8 + k];
        #pragma unroll
        for (int off = 32; off > 0; off >>= 1) s += __shfl_down(s, off);
        if (lane == 0){
          s *= SCALE_;
          if (l >= len && l != 0) s = -__builtin_inff();
          ssc[l] = s;
        }
      }
      __syncthreads();
      if (w == 0){
        float x0 = ssc[lane], x1 = ssc[lane + 64];
        float mx = fmaxf(x0, x1);
        #pragma unroll
        for (int off = 32; off > 0; off >>= 1) mx = fmaxf(mx, __shfl_xor(mx, off));
        float e0 = __expf(x0 - mx), e1 = __expf(x1 - mx);
        float sm = e0 + e1;
        #pragma unroll
        for (int off = 32; off > 0; off >>= 1) sm += __shfl_xor(sm, off);
        float inv = 1.f / sm;
        swt[lane] = e0 * inv;
        swt[lane + 64] = e1 * inv;
      }
      __syncthreads();
      int hh = tid * 4;
      float a0 = 0, a1 = 0, a2 = 0, a3 = 0;
      #pragma unroll 4
      for (int l = 0; l < LL; ++l){
        float wv = swt[l];
        const u16* dp = denc + ((size_t)(l * BB + b)) * HH + hh;
        s4v dv = *(const s4v*)dp;
        a0 += wv * bf2f((u16)dv[0]); a1 += wv * bf2f((u16)dv[1]);
        a2 += wv * bf2f((u16)dv[2]); a3 += wv * bf2f((u16)dv[3]);
      }
      u16* cp = ctxb + b * HH + hh;
      cp[0] = f2bf(a0); cp[1] = f2bf(a1); cp[2] = f2bf(a2); cp[3] = f2bf(a3);
    }
    gbar(bar, 64, epoch);

    // ---- Phase B: m = relu(ctx @ W1c^T + obs_part[t]) : 32 x 4096 ----
    {
      const int col0 = nb * 64 + w * 16;
      f4v a0 = {0.f,0.f,0.f,0.f}, a1 = {0.f,0.f,0.f,0.f};
      const u16* Bp = W1c + (size_t)(col0 + lr) * HH + lk;
      const u16* A0 = ctxb + lr * HH + lk;
      const u16* A1 = A0 + 16 * HH;
      #pragma unroll 8
      for (int ks = 0; ks < 32; ++ks){
        s8v va0 = *(const s8v*)(A0 + ks * 32);
        s8v va1 = *(const s8v*)(A1 + ks * 32);
        s8v vb  = *(const s8v*)(Bp + ks * 32);
        mfma16(a0, va0, vb);
        mfma16(a1, va1, vb);
      }
      const int rb = (lane >> 4) * 4, cc = col0 + lr;
      #pragma unroll
      for (int r = 0; r < 4; r++){
        int b = rb + r;
        float v0 = a0[r] + bf2f(obsp[((size_t)(t * BB + b)) * G4 + cc]);
        mb[b * G4 + cc] = f2bf(fmaxf(v0, 0.f));
        int bb2 = b + 16;
        float v1 = a1[r] + bf2f(obsp[((size_t)(t * BB + bb2)) * G4 + cc]);
        mb[bb2 * G4 + cc] = f2bf(fmaxf(v1, 0.f));
      }
    }
    gbar(bar, 64, epoch);

    // ---- Phase C: x = relu(m @ W2^T + b2) : 32 x 1024, waves split K ----
    {
      f4v a0 = {0.f,0.f,0.f,0.f}, a1 = {0.f,0.f,0.f,0.f};
      const u16* Bp = W2w + (size_t)(jc + lr) * G4 + w * HH + lk;
      const u16* A0 = mb + lr * G4 + w * HH + lk;
      const u16* A1 = A0 + 16 * G4;
      #pragma unroll 8
      for (int ks = 0; ks < 32; ++ks){
        s8v va0 = *(const s8v*)(A0 + ks * 32);
        s8v va1 = *(const s8v*)(A1 + ks * 32);
        s8v vb  = *(const s8v*)(Bp + ks * 32);
        mfma16(a0, va0, vb);
        mfma16(a1, va1, vb);
      }
      const int rb = (lane >> 4) * 4;
      #pragma unroll
      for (int r = 0; r < 4; r++){ gx[w][rb + r][lr] = a0[r]; gx[w][16 + rb + r][lr] = a1[r]; }
      __syncthreads();
      {
        float v0 = gx[0][eb][ejj] + gx[1][eb][ejj] + gx[2][eb][ejj] + gx[3][eb][ejj] + b2[jc + ejj];
        xb[eb * HH + jc + ejj] = f2bf(fmaxf(v0, 0.f));
        int b2e = eb + 16;
        float v1 = gx[0][b2e][ejj] + gx[1][b2e][ejj] + gx[2][b2e][ejj] + gx[3][b2e][ejj] + b2[jc + ejj];
        xb[b2e * HH + jc + ejj] = f2bf(fmaxf(v1, 0.f));
      }
    }
    gbar(bar, 64, epoch);

    // ---- Phase D: gates = x@WihL^T + h@WhhL^T + b; LSTM cell ----
    {
      const u16* hb = hbuf + (t & 1) * (BB * HH);
      f4v a0 = {0.f,0.f,0.f,0.f}, a1 = {0.f,0.f,0.f,0.f};
      const u16* Bx = WihL + (size_t)(w * HH + jc + lr) * HH + lk;
      const u16* Ax = xb + lr * HH + lk;
      #pragma unroll 8
      for (int ks = 0; ks < 32; ++ks){
        s8v va0 = *(const s8v*)(Ax + ks * 32);
        s8v va1 = *(const s8v*)(Ax + 16 * HH + ks * 32);
        s8v vb  = *(const s8v*)(Bx + ks * 32);
        mfma16(a0, va0, vb);
        mfma16(a1, va1, vb);
      }
      const u16* Bh = WhhL + (size_t)(w * HH + jc + lr) * HH + lk;
      const u16* Ah = hb + lr * HH + lk;
      #pragma unroll 8
      for (int ks = 0; ks < 32; ++ks){
        s8v va0 = *(const s8v*)(Ah + ks * 32);
        s8v va1 = *(const s8v*)(Ah + 16 * HH + ks * 32);
        s8v vb  = *(const s8v*)(Bh + ks * 32);
        mfma16(a0, va0, vb);
        mfma16(a1, va1, vb);
      }
      const int rb = (lane >> 4) * 4;
      #pragma unroll
      for (int r = 0; r < 4; r++){ gx[w][rb + r][lr] = a0[r]; gx[w][16 + rb + r][lr] = a1[r]; }
      __syncthreads();
      u16* ho = hbuf + ((t + 1) & 1) * (BB * HH);
      {
        int col = jc + ejj;
        float gi = gx[0][eb][ejj] + blstm[col];
        float gf = gx[1][eb][ejj] + blstm[1024 + col];
        float gg = gx[2][eb][ejj] + blstm[2048 + col];
        float go = gx[3][eb][ejj] + blstm[3072 + col];
        cr0 = sigf(gf) * cr0 + sigf(gi) * tanhf(gg);
        float h = sigf(go) * tanhf(cr0);
        out[(size_t)t * (BB * HH) + eb * HH + col] = h;
        hf[eb * HH + col] = h;
        ho[eb * HH + col] = f2bf(h);
        if (t == TT - 1){ out[1048576 + eb * HH + col] = h; out[1081344 + eb * HH + col] = cr0; }
        int b2e = eb + 16;
        float gi2 = gx[0][b2e][ejj] + blstm[col];
        float gf2 = gx[1][b2e][ejj] + blstm[1024 + col];
        float gg2 = gx[2][b2e][ejj] + blstm[2048 + col];
        float go2 = gx[3][b2e][ejj] + blstm[3072 + col];
        cr1 = sigf(gf2) * cr1 + sigf(gi2) * tanhf(gg2);
        float h2 = sigf(go2) * tanhf(cr1);
        out[(size_t)t * (BB * HH) + b2e * HH + col] = h2;
        hf[b2e * HH + col] = h2;
        ho[b2e * HH + col] = f2bf(h2);
        if (t == TT - 1){ out[1048576 + b2e * HH + col] = h2; out[1081344 + b2e * HH + col] = cr1; }
      }
    }
    gbar(bar, 64, epoch);
  }
}

// ---------- workspace layout (bytes; all offsets 256B-aligned) ----------
static constexpr size_t oWihE = 0;                      // 4096*512*2  = 4,194,304
static constexpr size_t oWhhE = oWihE + 4194304;        // 4096*1024*2 = 8,388,608
static constexpr size_t oAttnW= oWhhE + 8388608;        // 1024*1024*2 = 2,097,152
static constexpr size_t oW1C  = oAttnW+ 2097152;        // 4096*1024*2
static constexpr size_t oW1O  = oW1C  + 8388608;        // 4096*512*2
static constexpr size_t oW2   = oW1O  + 4194304;        // 1024*4096*2
static constexpr size_t oWihL = oW2   + 8388608;
static constexpr size_t oWhhL = oWihL + 8388608;
static constexpr size_t oBEnc = oWhhL + 8388608;        // 4096*4
static constexpr size_t oBL   = oBEnc + 16384;
static constexpr size_t oDemoT= oBL   + 16384;          // 4096*512*2
static constexpr size_t oObsB = oDemoT+ 4194304;        // 1024*512*2
static constexpr size_t oXih  = oObsB + 1048576;        // 4096*4096*2 = 33,554,432
static constexpr size_t oObsP = oXih  + 33554432;       // 1024*4096*2
static constexpr size_t oDEnc = oObsP + 8388608;        // 4096*1024*2
static constexpr size_t oAPrj = oDEnc + 8388608;        // 4096*1024*2
static constexpr size_t oHF   = oAPrj + 8388608;        // 32*1024*4
static constexpr size_t oHB   = oHF   + 131072;         // 2*32*1024*2
static constexpr size_t oCtx  = oHB   + 131072;         // 32*1024*2
static constexpr size_t oMB   = oCtx  + 65536;          // 32*4096*2
static constexpr size_t oXB   = oMB   + 262144;         // 32*1024*2
static constexpr size_t oBar  = oXB   + 65536;          // 256
// total ~117 MB

extern "C" void kernel_launch(void* const* d_in, const int* in_sizes, int n_in,
                              void* d_out, int out_size, void* d_ws, size_t ws_size,
                              hipStream_t stream)
{
  const float* demo = (const float*)d_in[0];
  const int*   lens = (const int*)  d_in[1];
  const float* obs  = (const float*)d_in[2];
  const float* h0   = (const float*)d_in[3];
  const float* c0   = (const float*)d_in[4];
  const float* eWih = (const float*)d_in[5];
  const float* eWhh = (const float*)d_in[6];
  const float* eBih = (const float*)d_in[7];
  const float* eBhh = (const float*)d_in[8];
  const float* aW   = (const float*)d_in[9];
  const float* aB   = (const float*)d_in[10];
  const float* W1   = (const float*)d_in[11];
  const float* B1   = (const float*)d_in[12];
  const float* W2   = (const float*)d_in[13];
  const float* B2   = (const float*)d_in[14];
  const float* lWih = (const float*)d_in[15];
  const float* lWhh = (const float*)d_in[16];
  const float* lBih = (const float*)d_in[17];
  const float* lBhh = (const float*)d_in[18];

  char* ws = (char*)d_ws;
  u16*  WihE = (u16*)(ws + oWihE);
  u16*  WhhE = (u16*)(ws + oWhhE);
  u16*  AttnW= (u16*)(ws + oAttnW);
  u16*  W1C  = (u16*)(ws + oW1C);
  u16*  W1O  = (u16*)(ws + oW1O);
  u16*  W2w  = (u16*)(ws + oW2);
  u16*  WihL = (u16*)(ws + oWihL);
  u16*  WhhL = (u16*)(ws + oWhhL);
  float* BEnc= (float*)(ws + oBEnc);
  float* BL  = (float*)(ws + oBL);
  u16*  DemoT= (u16*)(ws + oDemoT);
  u16*  ObsB = (u16*)(ws + oObsB);
  u16*  Xih  = (u16*)(ws + oXih);
  u16*  ObsP = (u16*)(ws + oObsP);
  u16*  DEnc = (u16*)(ws + oDEnc);
  u16*  APrj = (u16*)(ws + oAPrj);
  float* HF  = (float*)(ws + oHF);
  u16*  HB   = (u16*)(ws + oHB);
  u16*  Ctx  = (u16*)(ws + oCtx);
  u16*  MB   = (u16*)(ws + oMB);
  u16*  XB   = (u16*)(ws + oXB);
  u32*  Bar  = (u32*)(ws + oBar);

  // prep: weight/activation conversions
  k_convert<<<1024, 256, 0, stream>>>(eWih, WihE, G4 * FF);
  k_convert<<<1024, 256, 0, stream>>>(eWhh, WhhE, G4 * HH);
  k_convert<<<512,  256, 0, stream>>>(aW,   AttnW, HH * HH);
  k_split_w1<<<1024, 256, 0, stream>>>(W1, W1C, W1O);
  k_convert<<<1024, 256, 0, stream>>>(W2,   W2w,  HH * G4);
  k_convert<<<1024, 256, 0, stream>>>(lWih, WihL, G4 * HH);
  k_convert<<<1024, 256, 0, stream>>>(lWhh, WhhL, G4 * HH);
  k_addb<<<16, 256, 0, stream>>>(eBih, eBhh, BEnc, G4);
  k_addb<<<16, 256, 0, stream>>>(lBih, lBhh, BL, G4);
  k_demo_t<<<1024, 256, 0, stream>>>(demo, DemoT);
  k_convert<<<512, 256, 0, stream>>>(obs, ObsB, TT * BB * FF);
  hipMemsetAsync(Bar, 0, 256, stream);

  // big parallel GEMMs
  {
    dim3 g(LL * BB / 128, G4 / 128);  // (32,32)
    k_gemm_bt<0><<<g, 256, 0, stream>>>(DemoT, WihE, BEnc, Xih, LL * BB, G4, FF);
  }
  {
    dim3 g(TT * BB / 128, G4 / 128);  // (8,32)
    k_gemm_bt<0><<<g, 256, 0, stream>>>(ObsB, W1O, B1, ObsP, TT * BB, G4, FF);
  }

  // encoder recurrence (persistent, 64 blocks)
  k_encoder<<<64, 256, 0, stream>>>(WhhE, Xih, HB, DEnc, Bar);

  // attn projection
  {
    dim3 g(LL * BB / 128, HH / 128);  // (32,8)
    k_gemm_bt<0><<<g, 256, 0, stream>>>(DEnc, AttnW, aB, APrj, LL * BB, HH, HH);
  }

  // decoder (persistent, 64 blocks)
  k_decoder<<<64, 256, 0, stream>>>(APrj, DEnc, ObsP, W1C, W2w, WihL, WhhL,
                                    BL, B2, h0, c0, lens,
                                    HF, HB, Ctx, MB, XB, (float*)d_out, Bar + 16);
}

// Round 2
// 4577.412 us; speedup vs baseline: 1.2585x; 1.2585x over previous
//
#include <hip/hip_runtime.h>

typedef unsigned short u16;
typedef unsigned int   u32;
typedef short s8v __attribute__((ext_vector_type(8)));
typedef short s4v __attribute__((ext_vector_type(4)));
typedef float f4v __attribute__((ext_vector_type(4)));
typedef u32   u2v __attribute__((ext_vector_type(2)));

// Problem constants
#define TT 32
#define BB 32
#define LL 128
#define FF 512
#define HH 1024
#define G4 4096
#define SCALE_ 0.08838834764831845f   // 1/sqrt(128)

// ---------- helpers ----------
__device__ __forceinline__ u16 f2bf(float f){
  u32 u = __float_as_uint(f);
  u32 r = u + 0x7fffu + ((u >> 16) & 1u);   // RNE
  return (u16)(r >> 16);
}
__device__ __forceinline__ float bf2f(u16 s){ return __uint_as_float(((u32)s) << 16); }
__device__ __forceinline__ float sigf(float x){ return 1.f / (1.f + __expf(-x)); }

__device__ __forceinline__ void mfma16(f4v& d, s8v a, s8v b){
  asm("v_mfma_f32_16x16x32_bf16 %0, %1, %2, %0" : "+v"(d) : "v"(a), "v"(b));
}

typedef __attribute__((address_space(3))) u32 as3u32;
typedef __attribute__((address_space(1))) u32 as1u32;
__device__ __forceinline__ void glds16(const u16* g, u16* l){
  __builtin_amdgcn_global_load_lds((const as1u32*)g, (as3u32*)l, 16, 0, 0);
}

// ---- coherent (LLC-level, cross-XCD) accessors: bypass L1+L2 via sc0 sc1 ----
__device__ __forceinline__ s8v ldcc8(const u16* p){
  s8v v;
  asm volatile("global_load_dwordx4 %0, %1, off sc0 sc1" : "=v"(v) : "v"(p) : "memory");
  return v;
}
__device__ __forceinline__ f4v ldcc4f(const float* p){
  f4v v;
  asm volatile("global_load_dwordx4 %0, %1, off sc0 sc1" : "=v"(v) : "v"(p) : "memory");
  return v;
}
__device__ __forceinline__ void stcc_u16(u16* p, u16 v){
  u32 vv = v;
  asm volatile("global_store_short %0, %1, off sc0 sc1" :: "v"(p), "v"(vv) : "memory");
}
__device__ __forceinline__ void stcc_f32(float* p, float v){
  asm volatile("global_store_dword %0, %1, off sc0 sc1" :: "v"(p), "v"(v) : "memory");
}
__device__ __forceinline__ void stcc_2x32(void* p, u2v v){
  asm volatile("global_store_dwordx2 %0, %1, off sc0 sc1" :: "v"(p), "v"(v) : "memory");
}
__device__ __forceinline__ u32 poll_ld(const u32* p){
  u32 v;
  asm volatile("global_load_dword %0, %1, off sc0 sc1\n\ts_waitcnt vmcnt(0)"
               : "=v"(v) : "v"(p) : "memory");
  return v;
}
__device__ __forceinline__ void waitv0(){
  asm volatile("s_waitcnt vmcnt(0)" ::: "memory");
  __builtin_amdgcn_sched_barrier(0);
}

// device-scope grid barrier WITHOUT L2 invalidation.
// Correct because ALL cross-block data in these kernels moves via sc0sc1
// (write-through LLC) stores/loads; weights are read-only so plain-cached
// copies can never be stale. buffer_wbl2 on a (clean) L2 is cheap insurance.
__device__ __forceinline__ void gbar(u32* cnt, u32 nblk, u32& epoch){
  asm volatile("s_waitcnt vmcnt(0)" ::: "memory");   // drain own coherent stores
  __syncthreads();
  ++epoch;
  if (threadIdx.x == 0){
    asm volatile("buffer_wbl2 sc1\n\ts_waitcnt vmcnt(0)" ::: "memory");
    atomicAdd(cnt, 1u);
    u32 target = epoch * nblk;
    while (poll_ld(cnt) < target) __builtin_amdgcn_s_sleep(1);
  }
  __syncthreads();
}

// ---------- LDS staging with XOR swizzle (byte ^= (row&15)<<4) ----------
// src: [32][1024] u16, coherent; dst LDS 64KB, row stride 2048B.
__device__ __forceinline__ void stage32x1024(const u16* __restrict__ src, u16* lds){
  const int tid = threadIdx.x;
  const int row = tid >> 3, s0 = tid & 7;
  s8v tmp[16];
  const u16* p = src + row * HH + s0 * 8;
  #pragma unroll
  for (int i = 0; i < 16; i++) tmp[i] = ldcc8(p + i * 64);
  waitv0();
  char* base = (char*)lds + (row << 11);
  u32 x = (u32)(row & 15) << 4;
  #pragma unroll
  for (int i = 0; i < 16; i++){
    u32 cb = (u32)(s0 + 8 * i) << 4;
    *(s8v*)(base + (cb ^ x)) = tmp[i];
  }
}
__device__ __forceinline__ s8v ldsA(const u16* lds, int row, int cb){
  return *(const s8v*)((const char*)lds + (row << 11) + (cb ^ ((row & 15) << 4)));
}
// phase-C variant: per-wave [32][256] slice, row stride 512B
__device__ __forceinline__ void stageC(const u16* __restrict__ src, u16* ldsw, int lane){
  const int row = lane >> 1, s0 = lane & 1;
  s8v tmp[16];
  const u16* p = src + row * G4 + s0 * 8;
  #pragma unroll
  for (int i = 0; i < 16; i++) tmp[i] = ldcc8(p + i * 16);
  waitv0();
  char* base = (char*)ldsw + (row << 9);
  u32 x = (u32)(row & 15) << 4;
  #pragma unroll
  for (int i = 0; i < 16; i++){
    u32 cb = (u32)(s0 + 2 * i) << 4;
    *(s8v*)(base + (cb ^ x)) = tmp[i];
  }
}
__device__ __forceinline__ s8v ldsC(const u16* ldsw, int row, int cb){
  return *(const s8v*)((const char*)ldsw + (row << 9) + (cb ^ ((row & 15) << 4)));
}

// ---------- prep kernels ----------
__global__ void k_convert(const float* __restrict__ src, u16* __restrict__ dst, int n){
  int i = blockIdx.x * blockDim.x + threadIdx.x;
  int st = gridDim.x * blockDim.x;
  for (; i < n; i += st) dst[i] = f2bf(src[i]);
}
__global__ void k_split_w1(const float* __restrict__ w1, u16* __restrict__ w1c, u16* __restrict__ w1o){
  int i = blockIdx.x * blockDim.x + threadIdx.x;
  int st = gridDim.x * blockDim.x;
  const int n = G4 * (FF + HH);
  for (; i < n; i += st){
    int j = i / 1536, k = i - j * 1536;
    u16 v = f2bf(w1[i]);
    if (k < HH) w1c[j * HH + k] = v;
    else        w1o[j * FF + (k - HH)] = v;
  }
}
__global__ void k_addb(const float* __restrict__ a, const float* __restrict__ b,
                       float* __restrict__ o, int n){
  int i = blockIdx.x * blockDim.x + threadIdx.x;
  int st = gridDim.x * blockDim.x;
  for (; i < n; i += st) o[i] = a[i] + b[i];
}
__global__ void k_demo_t(const float* __restrict__ d, u16* __restrict__ o){
  const int n = LL * BB * FF;
  int i = blockIdx.x * blockDim.x + threadIdx.x;
  int st = gridDim.x * blockDim.x;
  for (; i < n; i += st){
    int f = i & 511;
    int row = i >> 9;
    int l = row >> 5, b = row & 31;
    o[i] = f2bf(d[(size_t)b * (LL * FF) + l * FF + f]);
  }
}

// ---------- generic GEMM (unchanged from round 1) ----------
template<int RELU>
__global__ void __launch_bounds__(256) k_gemm_bt(const u16* __restrict__ A, const u16* __restrict__ B,
        const float* __restrict__ bias, u16* __restrict__ C, int M, int N, int K)
{
  __shared__ u16 As[128 * 64];
  __shared__ u16 Bs[128 * 64];
  const int tid = threadIdx.x;
  const int lane = tid & 63, wave = tid >> 6;
  const int m0 = blockIdx.x * 128, n0 = blockIdx.y * 128;
  const int wm = wave >> 1, wn = wave & 1;
  const int lr = lane & 15, lk = (lane >> 4) * 8;
  f4v acc[4][4];
  #pragma unroll
  for (int i = 0; i < 4; i++)
    #pragma unroll
    for (int j = 0; j < 4; j++) acc[i][j] = f4v{0.f, 0.f, 0.f, 0.f};

  for (int kt = 0; kt < K; kt += 64){
    #pragma unroll
    for (int i = 0; i < 4; i++){
      int c = tid + i * 256;
      int row = c >> 3, cc = (c & 7) * 8;
      glds16(A + (size_t)(m0 + row) * K + kt + cc, &As[c * 8]);
      glds16(B + (size_t)(n0 + row) * K + kt + cc, &Bs[c * 8]);
    }
    __syncthreads();
    #pragma unroll
    for (int ks = 0; ks < 2; ++ks){
      int ko = ks * 32 + lk;
      s8v av[4], bv[4];
      #pragma unroll
      for (int m = 0; m < 4; m++) av[m] = *(const s8v*)&As[(wm * 64 + m * 16 + lr) * 64 + ko];
      #pragma unroll
      for (int n = 0; n < 4; n++) bv[n] = *(const s8v*)&Bs[(wn * 64 + n * 16 + lr) * 64 + ko];
      #pragma unroll
      for (int m = 0; m < 4; m++)
        #pragma unroll
        for (int n = 0; n < 4; n++) mfma16(acc[m][n], av[m], bv[n]);
    }
    __syncthreads();
  }
  const int r0 = (lane >> 4) * 4;
  #pragma unroll
  for (int m = 0; m < 4; m++){
    #pragma unroll
    for (int n = 0; n < 4; n++){
      int col = n0 + wn * 64 + n * 16 + lr;
      float bc = bias[col];
      #pragma unroll
      for (int r = 0; r < 4; r++){
        int row = m0 + wm * 64 + m * 16 + r0 + r;
        float v = acc[m][n][r] + bc;
        if (RELU) v = fmaxf(v, 0.f);
        C[(size_t)row * N + col] = f2bf(v);
      }
    }
  }
}

// ---------- encoder ----------
union SMemE { u16 stage[32768]; float gx[4][32][16]; };

__global__ void __launch_bounds__(256) k_encoder(const u16* __restrict__ Whh, const u16* __restrict__ Xih,
      u16* __restrict__ hbuf, u16* __restrict__ denc, u32* bar)
{
  __shared__ SMemE sm;
  const int nb = blockIdx.x, tid = threadIdx.x;
  const int lane = tid & 63, g = tid >> 6;
  const int jc = nb * 16;
  const int lr = lane & 15, lk = (lane >> 4) * 8;
  const int eb = tid >> 4, ejj = tid & 15;

  for (int i = tid; i < 512; i += 256){
    int b = i >> 4, jj = i & 15;
    stcc_u16(&hbuf[b * HH + jc + jj], 0);
  }
  float cr0 = 0.f, cr1 = 0.f;
  u32 epoch = 0;
  gbar(bar, 64, epoch);

  const u16* Wb = Whh + (size_t)(g * HH + jc + lr) * HH + lk;
  const int rb = (lane >> 4) * 4;
  for (int l = 0; l < LL; ++l){
    const u16* hb = hbuf + (l & 1) * (BB * HH);
    stage32x1024(hb, sm.stage);
    __syncthreads();
    f4v a0 = {0.f,0.f,0.f,0.f}, a1 = {0.f,0.f,0.f,0.f};
    #pragma unroll 8
    for (int ks = 0; ks < 32; ++ks){
      int cb = (lk + ks * 32) * 2;
      s8v va0 = ldsA(sm.stage, lr,      cb);
      s8v va1 = ldsA(sm.stage, lr + 16, cb);
      s8v vb  = *(const s8v*)(Wb + ks * 32);
      mfma16(a0, va0, vb);
      mfma16(a1, va1, vb);
    }
    __syncthreads();              // stage dead -> gx overlay
    #pragma unroll
    for (int r = 0; r < 4; r++){ sm.gx[g][rb + r][lr] = a0[r]; sm.gx[g][16 + rb + r][lr] = a1[r]; }
    __syncthreads();
    u16* ho = hbuf + ((l + 1) & 1) * (BB * HH);
    {
      const u16* xr = Xih + ((size_t)(l * BB + eb)) * G4 + jc + ejj;
      float gi = sm.gx[0][eb][ejj] + bf2f(xr[0]);
      float gf = sm.gx[1][eb][ejj] + bf2f(xr[1024]);
      float gg = sm.gx[2][eb][ejj] + bf2f(xr[2048]);
      float go = sm.gx[3][eb][ejj] + bf2f(xr[3072]);
      cr0 = sigf(gf) * cr0 + sigf(gi) * tanhf(gg);
      float h = sigf(go) * tanhf(cr0);
      u16 hv = f2bf(h);
      stcc_u16(&ho[eb * HH + jc + ejj], hv);
      stcc_u16(&denc[((size_t)(l * BB + eb)) * HH + jc + ejj], hv);
    }
    {
      int b2 = eb + 16;
      const u16* xr = Xih + ((size_t)(l * BB + b2)) * G4 + jc + ejj;
      float gi = sm.gx[0][b2][ejj] + bf2f(xr[0]);
      float gf = sm.gx[1][b2][ejj] + bf2f(xr[1024]);
      float gg = sm.gx[2][b2][ejj] + bf2f(xr[2048]);
      float go = sm.gx[3][b2][ejj] + bf2f(xr[3072]);
      cr1 = sigf(gf) * cr1 + sigf(gi) * tanhf(gg);
      float h = sigf(go) * tanhf(cr1);
      u16 hv = f2bf(h);
      stcc_u16(&ho[b2 * HH + jc + ejj], hv);
      stcc_u16(&denc[((size_t)(l * BB + b2)) * HH + jc + ejj], hv);
    }
    gbar(bar, 64, epoch);
  }
}

// ---------- decoder ----------
union SMemD {
  u16 stage[32768];
  float gx[4][32][16];
  struct { float ssc[128]; float swt[128]; } a;
};

__global__ void __launch_bounds__(256) k_decoder(
    const u16* __restrict__ aproj, const u16* __restrict__ denc, const u16* __restrict__ obsp,
    const u16* __restrict__ W1c, const u16* __restrict__ W2w, const u16* __restrict__ WihL,
    const u16* __restrict__ WhhL, const float* __restrict__ blstm, const float* __restrict__ b2,
    const float* __restrict__ h0, const float* __restrict__ c0, const int* __restrict__ lens,
    float* __restrict__ hf, u16* __restrict__ hbuf, u16* __restrict__ ctxb,
    u16* __restrict__ mb, u16* __restrict__ xb, float* __restrict__ out, u32* bar)
{
  __shared__ SMemD sm;
  const int nb = blockIdx.x, tid = threadIdx.x;
  const int lane = tid & 63, w = tid >> 6;
  const int jc = nb * 16;
  const int lr = lane & 15, lk = (lane >> 4) * 8;
  const int eb = tid >> 4, ejj = tid & 15;
  const int rb = (lane >> 4) * 4;

  float cr0, cr1;
  {
    float hv0 = h0[eb * HH + jc + ejj];
    float hv1 = h0[(eb + 16) * HH + jc + ejj];
    stcc_f32(&hf[eb * HH + jc + ejj], hv0);
    stcc_f32(&hf[(eb + 16) * HH + jc + ejj], hv1);
    stcc_u16(&hbuf[eb * HH + jc + ejj], f2bf(hv0));
    stcc_u16(&hbuf[(eb + 16) * HH + jc + ejj], f2bf(hv1));
    cr0 = c0[eb * HH + jc + ejj];
    cr1 = c0[(eb + 16) * HH + jc + ejj];
  }
  u32 epoch = 0;
  gbar(bar, 64, epoch);

  for (int t = 0; t < TT; ++t){
    // ---- Phase A: scores -> softmax -> ctx (blocks 0..31) ----
    if (nb < BB){
      const int b = nb;
      const int len = lens[b];
      f4v h4[4];
      const float* hp = hf + b * HH + lane * 16;
      #pragma unroll
      for (int i = 0; i < 4; i++) h4[i] = ldcc4f(hp + i * 4);
      waitv0();
      float hr[16];
      #pragma unroll
      for (int i = 0; i < 16; i++) hr[i] = h4[i >> 2][i & 3];
      for (int i = 0; i < 32; ++i){
        int l = w * 32 + i;
        const u16* ap = aproj + ((size_t)(l * BB + b)) * HH + lane * 16;
        s8v v0 = *(const s8v*)ap;
        s8v v1 = *(const s8v*)(ap + 8);
        float s = 0.f;
        #pragma unroll
        for (int k = 0; k < 8; k++) s += bf2f((u16)v0[k]) * hr[k];
        #pragma unroll
        for (int k = 0; k < 8; k++) s += bf2f((u16)v1[k]) * hr[8 + k];
        #pragma unroll
        for (int off = 32; off > 0; off >>= 1) s += __shfl_down(s, off);
        if (lane == 0){
          s *= SCALE_;
          if (l >= len && l != 0) s = -__builtin_inff();
          sm.a.ssc[l] = s;
        }
      }
      __syncthreads();
      if (w == 0){
        float x0 = sm.a.ssc[lane], x1 = sm.a.ssc[lane + 64];
        float mx = fmaxf(x0, x1);
        #pragma unroll
        for (int off = 32; off > 0; off >>= 1) mx = fmaxf(mx, __shfl_xor(mx, off));
        float e0 = __expf(x0 - mx), e1 = __expf(x1 - mx);
        float smv = e0 + e1;
        #pragma unroll
        for (int off = 32; off > 0; off >>= 1) smv += __shfl_xor(smv, off);
        float inv = 1.f / smv;
        sm.a.swt[lane] = e0 * inv;
        sm.a.swt[lane + 64] = e1 * inv;
      }
      __syncthreads();
      int hh = tid * 4;
      float a0 = 0, a1 = 0, a2 = 0, a3 = 0;
      #pragma unroll 4
      for (int l = 0; l < LL; ++l){
        float wv = sm.a.swt[l];
        const u16* dp = denc + ((size_t)(l * BB + b)) * HH + hh;
        s4v dv = *(const s4v*)dp;
        a0 += wv * bf2f((u16)dv[0]); a1 += wv * bf2f((u16)dv[1]);
        a2 += wv * bf2f((u16)dv[2]); a3 += wv * bf2f((u16)dv[3]);
      }
      u2v pk;
      pk[0] = ((u32)f2bf(a1) << 16) | f2bf(a0);
      pk[1] = ((u32)f2bf(a3) << 16) | f2bf(a2);
      stcc_2x32(ctxb + b * HH + hh, pk);
    }
    gbar(bar, 64, epoch);

    // ---- Phase B: m = relu(ctx @ W1c^T + obs_part[t]) ----
    {
      stage32x1024(ctxb, sm.stage);
      __syncthreads();
      const int col0 = nb * 64 + w * 16;
      f4v a0 = {0.f,0.f,0.f,0.f}, a1 = {0.f,0.f,0.f,0.f};
      const u16* Bp = W1c + (size_t)(col0 + lr) * HH + lk;
      #pragma unroll 8
      for (int ks = 0; ks < 32; ++ks){
        int cb = (lk + ks * 32) * 2;
        s8v va0 = ldsA(sm.stage, lr,      cb);
        s8v va1 = ldsA(sm.stage, lr + 16, cb);
        s8v vb  = *(const s8v*)(Bp + ks * 32);
        mfma16(a0, va0, vb);
        mfma16(a1, va1, vb);
      }
      const int cc = col0 + lr;
      #pragma unroll
      for (int r = 0; r < 4; r++){
        int b = rb + r;
        float v0 = a0[r] + bf2f(obsp[((size_t)(t * BB + b)) * G4 + cc]);
        stcc_u16(&mb[b * G4 + cc], f2bf(fmaxf(v0, 0.f)));
        int bb2 = b + 16;
        float v1 = a1[r] + bf2f(obsp[((size_t)(t * BB + bb2)) * G4 + cc]);
        stcc_u16(&mb[bb2 * G4 + cc], f2bf(fmaxf(v1, 0.f)));
      }
    }
    gbar(bar, 64, epoch);

    // ---- Phase C: x = relu(m @ W2^T + b2), waves K-split, 4 staged chunks ----
    {
      f4v a0 = {0.f,0.f,0.f,0.f}, a1 = {0.f,0.f,0.f,0.f};
      u16* ldsw = sm.stage + w * 8192;
      const u16* Bp = W2w + (size_t)(jc + lr) * G4 + w * HH + lk;
      for (int c = 0; c < 4; ++c){
        stageC(mb + w * HH + c * 256, ldsw, lane);
        __syncthreads();
        #pragma unroll
        for (int ks = 0; ks < 8; ++ks){
          int cb = (lk + ks * 32) * 2;
          s8v va0 = ldsC(ldsw, lr,      cb);
          s8v va1 = ldsC(ldsw, lr + 16, cb);
          s8v vb  = *(const s8v*)(Bp + c * 256 + ks * 32);
          mfma16(a0, va0, vb);
          mfma16(a1, va1, vb);
        }
        __syncthreads();
      }
      #pragma unroll
      for (int r = 0; r < 4; r++){ sm.gx[w][rb + r][lr] = a0[r]; sm.gx[w][16 + rb + r][lr] = a1[r]; }
      __syncthreads();
      {
        float v0 = sm.gx[0][eb][ejj] + sm.gx[1][eb][ejj] + sm.gx[2][eb][ejj] + sm.gx[3][eb][ejj] + b2[jc + ejj];
        stcc_u16(&xb[eb * HH + jc + ejj], f2bf(fmaxf(v0, 0.f)));
        int b2e = eb + 16;
        float v1 = sm.gx[0][b2e][ejj] + sm.gx[1][b2e][ejj] + sm.gx[2][b2e][ejj] + sm.gx[3][b2e][ejj] + b2[jc + ejj];
        stcc_u16(&xb[b2e * HH + jc + ejj], f2bf(fmaxf(v1, 0.f)));
      }
    }
    gbar(bar, 64, epoch);

    // ---- Phase D: gates = x@WihL^T + h@WhhL^T + b; LSTM cell ----
    {
      f4v a0 = {0.f,0.f,0.f,0.f}, a1 = {0.f,0.f,0.f,0.f};
      stage32x1024(xb, sm.stage);
      __syncthreads();
      const u16* Bx = WihL + (size_t)(w * HH + jc + lr) * HH + lk;
      #pragma unroll 8
      for (int ks = 0; ks < 32; ++ks){
        int cb = (lk + ks * 32) * 2;
        s8v va0 = ldsA(sm.stage, lr,      cb);
        s8v va1 = ldsA(sm.stage, lr + 16, cb);
        s8v vb  = *(const s8v*)(Bx + ks * 32);
        mfma16(a0, va0, vb);
        mfma16(a1, va1, vb);
      }
      __syncthreads();
      stage32x1024(hbuf + (t & 1) * (BB * HH), sm.stage);
      __syncthreads();
      const u16* Bh = WhhL + (size_t)(w * HH + jc + lr) * HH + lk;
      #pragma unroll 8
      for (int ks = 0; ks < 32; ++ks){
        int cb = (lk + ks * 32) * 2;
        s8v va0 = ldsA(sm.stage, lr,      cb);
        s8v va1 = ldsA(sm.stage, lr + 16, cb);
        s8v vb  = *(const s8v*)(Bh + ks * 32);
        mfma16(a0, va0, vb);
        mfma16(a1, va1, vb);
      }
      __syncthreads();
      #pragma unroll
      for (int r = 0; r < 4; r++){ sm.gx[w][rb + r][lr] = a0[r]; sm.gx[w][16 + rb + r][lr] = a1[r]; }
      __syncthreads();
      u16* ho = hbuf + ((t + 1) & 1) * (BB * HH);
      {
        int col = jc + ejj;
        float gi = sm.gx[0][eb][ejj] + blstm[col];
        float gf = sm.gx[1][eb][ejj] + blstm[1024 + col];
        float gg = sm.gx[2][eb][ejj] + blstm[2048 + col];
        float go = sm.gx[3][eb][ejj] + blstm[3072 + col];
        cr0 = sigf(gf) * cr0 + sigf(gi) * tanhf(gg);
        float h = sigf(go) * tanhf(cr0);
        stcc_f32(&out[(size_t)t * (BB * HH) + eb * HH + col], h);
        stcc_f32(&hf[eb * HH + col], h);
        stcc_u16(&ho[eb * HH + col], f2bf(h));
        if (t == TT - 1){ stcc_f32(&out[1048576 + eb * HH + col], h); stcc_f32(&out[1081344 + eb * HH + col], cr0); }
        int b2e = eb + 16;
        float gi2 = sm.gx[0][b2e][ejj] + blstm[col];
        float gf2 = sm.gx[1][b2e][ejj] + blstm[1024 + col];
        float gg2 = sm.gx[2][b2e][ejj] + blstm[2048 + col];
        float go2 = sm.gx[3][b2e][ejj] + blstm[3072 + col];
        cr1 = sigf(gf2) * cr1 + sigf(gi2) * tanhf(gg2);
        float h2 = sigf(go2) * tanhf(cr1);
        stcc_f32(&out[(size_t)t * (BB * HH) + b2e * HH + col], h2);
        stcc_f32(&hf[b2e * HH + col], h2);
        stcc_u16(&ho[b2e * HH + col], f2bf(h2));
        if (t == TT - 1){ stcc_f32(&out[1048576 + b2e * HH + col], h2); stcc_f32(&out[1081344 + b2e * HH + col], cr1); }
      }
    }
    gbar(bar, 64, epoch);
  }
}

// ---------- workspace layout ----------
static constexpr size_t oWihE = 0;
static constexpr size_t oWhhE = oWihE + 4194304;
static constexpr size_t oAttnW= oWhhE + 8388608;
static constexpr size_t oW1C  = oAttnW+ 2097152;
static constexpr size_t oW1O  = oW1C  + 8388608;
static constexpr size_t oW2   = oW1O  + 4194304;
static constexpr size_t oWihL = oW2   + 8388608;
static constexpr size_t oWhhL = oWihL + 8388608;
static constexpr size_t oBEnc = oWhhL + 8388608;
static constexpr size_t oBL   = oBEnc + 16384;
static constexpr size_t oDemoT= oBL   + 16384;
static constexpr size_t oObsB = oDemoT+ 4194304;
static constexpr size_t oXih  = oObsB + 1048576;
static constexpr size_t oObsP = oXih  + 33554432;
static constexpr size_t oDEnc = oObsP + 8388608;
static constexpr size_t oAPrj = oDEnc + 8388608;
static constexpr size_t oHF   = oAPrj + 8388608;
static constexpr size_t oHB   = oHF   + 131072;
static constexpr size_t oCtx  = oHB   + 131072;
static constexpr size_t oMB   = oCtx  + 65536;
static constexpr size_t oXB   = oMB   + 262144;
static constexpr size_t oBar  = oXB   + 65536;

extern "C" void kernel_launch(void* const* d_in, const int* in_sizes, int n_in,
                              void* d_out, int out_size, void* d_ws, size_t ws_size,
                              hipStream_t stream)
{
  const float* demo = (const float*)d_in[0];
  const int*   lens = (const int*)  d_in[1];
  const float* obs  = (const float*)d_in[2];
  const float* h0   = (const float*)d_in[3];
  const float* c0   = (const float*)d_in[4];
  const float* eWih = (const float*)d_in[5];
  const float* eWhh = (const float*)d_in[6];
  const float* eBih = (const float*)d_in[7];
  const float* eBhh = (const float*)d_in[8];
  const float* aW   = (const float*)d_in[9];
  const float* aB   = (const float*)d_in[10];
  const float* W1   = (const float*)d_in[11];
  const float* B1   = (const float*)d_in[12];
  const float* W2   = (const float*)d_in[13];
  const float* B2   = (const float*)d_in[14];
  const float* lWih = (const float*)d_in[15];
  const float* lWhh = (const float*)d_in[16];
  const float* lBih = (const float*)d_in[17];
  const float* lBhh = (const float*)d_in[18];

  char* ws = (char*)d_ws;
  u16*  WihE = (u16*)(ws + oWihE);
  u16*  WhhE = (u16*)(ws + oWhhE);
  u16*  AttnW= (u16*)(ws + oAttnW);
  u16*  W1C  = (u16*)(ws + oW1C);
  u16*  W1O  = (u16*)(ws + oW1O);
  u16*  W2w  = (u16*)(ws + oW2);
  u16*  WihL = (u16*)(ws + oWihL);
  u16*  WhhL = (u16*)(ws + oWhhL);
  float* BEnc= (float*)(ws + oBEnc);
  float* BL  = (float*)(ws + oBL);
  u16*  DemoT= (u16*)(ws + oDemoT);
  u16*  ObsB = (u16*)(ws + oObsB);
  u16*  Xih  = (u16*)(ws + oXih);
  u16*  ObsP = (u16*)(ws + oObsP);
  u16*  DEnc = (u16*)(ws + oDEnc);
  u16*  APrj = (u16*)(ws + oAPrj);
  float* HF  = (float*)(ws + oHF);
  u16*  HB   = (u16*)(ws + oHB);
  u16*  Ctx  = (u16*)(ws + oCtx);
  u16*  MB   = (u16*)(ws + oMB);
  u16*  XB   = (u16*)(ws + oXB);
  u32*  Bar  = (u32*)(ws + oBar);

  k_convert<<<1024, 256, 0, stream>>>(eWih, WihE, G4 * FF);
  k_convert<<<1024, 256, 0, stream>>>(eWhh, WhhE, G4 * HH);
  k_convert<<<512,  256, 0, stream>>>(aW,   AttnW, HH * HH);
  k_split_w1<<<1024, 256, 0, stream>>>(W1, W1C, W1O);
  k_convert<<<1024, 256, 0, stream>>>(W2,   W2w,  HH * G4);
  k_convert<<<1024, 256, 0, stream>>>(lWih, WihL, G4 * HH);
  k_convert<<<1024, 256, 0, stream>>>(lWhh, WhhL, G4 * HH);
  k_addb<<<16, 256, 0, stream>>>(eBih, eBhh, BEnc, G4);
  k_addb<<<16, 256, 0, stream>>>(lBih, lBhh, BL, G4);
  k_demo_t<<<1024, 256, 0, stream>>>(demo, DemoT);
  k_convert<<<512, 256, 0, stream>>>(obs, ObsB, TT * BB * FF);
  hipMemsetAsync(Bar, 0, 256, stream);

  {
    dim3 g(LL * BB / 128, G4 / 128);
    k_gemm_bt<0><<<g, 256, 0, stream>>>(DemoT, WihE, BEnc, Xih, LL * BB, G4, FF);
  }
  {
    dim3 g(TT * BB / 128, G4 / 128);
    k_gemm_bt<0><<<g, 256, 0, stream>>>(ObsB, W1O, B1, ObsP, TT * BB, G4, FF);
  }

  k_encoder<<<64, 256, 0, stream>>>(WhhE, Xih, HB, DEnc, Bar);

  {
    dim3 g(LL * BB / 128, HH / 128);
    k_gemm_bt<0><<<g, 256, 0, stream>>>(DEnc, AttnW, aB, APrj, LL * BB, HH, HH);
  }

  k_decoder<<<64, 256, 0, stream>>>(APrj, DEnc, ObsP, W1C, W2w, WihL, WhhL,
                                    BL, B2, h0, c0, lens,
                                    HF, HB, Ctx, MB, XB, (float*)d_out, Bar + 16);
}

// Round 4
// 4317.577 us; speedup vs baseline: 1.3343x; 1.0602x over previous
//
#include <hip/hip_runtime.h>

typedef unsigned short u16;
typedef unsigned int   u32;
typedef short s8v __attribute__((ext_vector_type(8)));
typedef short s4v __attribute__((ext_vector_type(4)));
typedef float f4v __attribute__((ext_vector_type(4)));
typedef u32   u2v __attribute__((ext_vector_type(2)));

// Problem constants
#define TT 32
#define BB 32
#define LL 128
#define FF 512
#define HH 1024
#define G4 4096
#define SCALE_ 0.08838834764831845f   // 1/sqrt(128)

// ---------- helpers ----------
__device__ __forceinline__ u16 f2bf(float f){
  u32 u = __float_as_uint(f);
  u32 r = u + 0x7fffu + ((u >> 16) & 1u);   // RNE
  return (u16)(r >> 16);
}
__device__ __forceinline__ float bf2f(u16 s){ return __uint_as_float(((u32)s) << 16); }
__device__ __forceinline__ float sigf(float x){ return 1.f / (1.f + __expf(-x)); }

__device__ __forceinline__ void mfma16(f4v& d, s8v a, s8v b){
  asm("v_mfma_f32_16x16x32_bf16 %0, %1, %2, %0" : "+v"(d) : "v"(a), "v"(b));
}

typedef __attribute__((address_space(3))) u32 as3u32;
typedef __attribute__((address_space(1))) u32 as1u32;
__device__ __forceinline__ void glds16(const u16* g, u16* l){
  __builtin_amdgcn_global_load_lds((const as1u32*)g, (as3u32*)l, 16, 0, 0);
}

// ---- coherent (LLC-level, cross-XCD) accessors: bypass L1+L2 via sc0 sc1 ----
__device__ __forceinline__ s8v ldcc8(const u16* p){
  s8v v;
  asm volatile("global_load_dwordx4 %0, %1, off sc0 sc1" : "=v"(v) : "v"(p) : "memory");
  return v;
}
__device__ __forceinline__ f4v ldcc4f(const float* p){
  f4v v;
  asm volatile("global_load_dwordx4 %0, %1, off sc0 sc1" : "=v"(v) : "v"(p) : "memory");
  return v;
}
__device__ __forceinline__ void stcc_u16(u16* p, u16 v){
  u32 vv = v;
  asm volatile("global_store_short %0, %1, off sc0 sc1" :: "v"(p), "v"(vv) : "memory");
}
__device__ __forceinline__ void stcc_f32(float* p, float v){
  asm volatile("global_store_dword %0, %1, off sc0 sc1" :: "v"(p), "v"(v) : "memory");
}
__device__ __forceinline__ void stcc_2x32(void* p, u2v v){
  asm volatile("global_store_dwordx2 %0, %1, off sc0 sc1" :: "v"(p), "v"(v) : "memory");
}
__device__ __forceinline__ u32 poll_ld(const u32* p){
  u32 v;
  asm volatile("global_load_dword %0, %1, off sc0 sc1\n\ts_waitcnt vmcnt(0)"
               : "=v"(v) : "v"(p) : "memory");
  return v;
}
__device__ __forceinline__ void waitv0(){
  asm volatile("s_waitcnt vmcnt(0)" ::: "memory");
  __builtin_amdgcn_sched_barrier(0);
}

// grid barrier: NO cache maintenance. All cross-block data moves via sc0sc1
// (write-through to the coherent point, never left dirty in L2), so vmcnt(0)
// before the atomic is the full release; the sc0sc1 poll is the acquire.
__device__ __forceinline__ void gbar(u32* cnt, u32 nblk, u32& epoch){
  asm volatile("s_waitcnt vmcnt(0)" ::: "memory");   // own coherent stores done
  __syncthreads();
  ++epoch;
  if (threadIdx.x == 0){
    atomicAdd(cnt, 1u);
    u32 target = epoch * nblk;
    while (poll_ld(cnt) < target) __builtin_amdgcn_s_sleep(1);
  }
  __syncthreads();
}

// ---------- staging: [32][1024] u16 -> LDS, XOR swizzle (byte ^= (row&15)<<4) ----------
__device__ __forceinline__ void stage_issue(const u16* __restrict__ src, s8v* tmp){
  const int tid = threadIdx.x;
  const int row = tid >> 3, s0 = tid & 7;
  const u16* p = src + row * HH + s0 * 8;
  #pragma unroll
  for (int i = 0; i < 16; i++) tmp[i] = ldcc8(p + i * 64);
}
__device__ __forceinline__ void stage_commit(const s8v* tmp, u16* lds){
  const int tid = threadIdx.x;
  const int row = tid >> 3, s0 = tid & 7;
  char* base = (char*)lds + (row << 11);
  u32 x = (u32)(row & 15) << 4;
  #pragma unroll
  for (int i = 0; i < 16; i++){
    u32 cb = (u32)(s0 + 8 * i) << 4;
    *(s8v*)(base + (cb ^ x)) = tmp[i];
  }
}
__device__ __forceinline__ s8v ldsA(const u16* lds, int row, int cb){
  return *(const s8v*)((const char*)lds + (row << 11) + (cb ^ ((row & 15) << 4)));
}
// phase-C per-wave [32][256] slice (16KB), row stride 512B
__device__ __forceinline__ void stageC_issue(const u16* __restrict__ src, s8v* tmp, int lane){
  const int row = lane >> 1, s0 = lane & 1;
  const u16* p = src + row * G4 + s0 * 8;
  #pragma unroll
  for (int i = 0; i < 16; i++) tmp[i] = ldcc8(p + i * 16);
}
__device__ __forceinline__ void stageC_commit(const s8v* tmp, u16* ldsw, int lane){
  const int row = lane >> 1, s0 = lane & 1;
  char* base = (char*)ldsw + (row << 9);
  u32 x = (u32)(row & 15) << 4;
  #pragma unroll
  for (int i = 0; i < 16; i++){
    u32 cb = (u32)(s0 + 2 * i) << 4;
    *(s8v*)(base + (cb ^ x)) = tmp[i];
  }
}
__device__ __forceinline__ s8v ldsC(const u16* ldsw, int row, int cb){
  return *(const s8v*)((const char*)ldsw + (row << 9) + (cb ^ ((row & 15) << 4)));
}

// ---------- prep kernels ----------
__global__ void k_convert(const float* __restrict__ src, u16* __restrict__ dst, int n){
  int i = blockIdx.x * blockDim.x + threadIdx.x;
  int st = gridDim.x * blockDim.x;
  for (; i < n; i += st) dst[i] = f2bf(src[i]);
}
__global__ void k_split_w1(const float* __restrict__ w1, u16* __restrict__ w1c, u16* __restrict__ w1o){
  int i = blockIdx.x * blockDim.x + threadIdx.x;
  int st = gridDim.x * blockDim.x;
  const int n = G4 * (FF + HH);
  for (; i < n; i += st){
    int j = i / 1536, k = i - j * 1536;
    u16 v = f2bf(w1[i]);
    if (k < HH) w1c[j * HH + k] = v;
    else        w1o[j * FF + (k - HH)] = v;
  }
}
__global__ void k_addb(const float* __restrict__ a, const float* __restrict__ b,
                       float* __restrict__ o, int n){
  int i = blockIdx.x * blockDim.x + threadIdx.x;
  int st = gridDim.x * blockDim.x;
  for (; i < n; i += st) o[i] = a[i] + b[i];
}
__global__ void k_demo_t(const float* __restrict__ d, u16* __restrict__ o){
  const int n = LL * BB * FF;
  int i = blockIdx.x * blockDim.x + threadIdx.x;
  int st = gridDim.x * blockDim.x;
  for (; i < n; i += st){
    int f = i & 511;
    int row = i >> 9;
    int l = row >> 5, b = row & 31;
    o[i] = f2bf(d[(size_t)b * (LL * FF) + l * FF + f]);
  }
}

// ---------- generic GEMM (unchanged) ----------
template<int RELU>
__global__ void __launch_bounds__(256) k_gemm_bt(const u16* __restrict__ A, const u16* __restrict__ B,
        const float* __restrict__ bias, u16* __restrict__ C, int M, int N, int K)
{
  __shared__ u16 As[128 * 64];
  __shared__ u16 Bs[128 * 64];
  const int tid = threadIdx.x;
  const int lane = tid & 63, wave = tid >> 6;
  const int m0 = blockIdx.x * 128, n0 = blockIdx.y * 128;
  const int wm = wave >> 1, wn = wave & 1;
  const int lr = lane & 15, lk = (lane >> 4) * 8;
  f4v acc[4][4];
  #pragma unroll
  for (int i = 0; i < 4; i++)
    #pragma unroll
    for (int j = 0; j < 4; j++) acc[i][j] = f4v{0.f, 0.f, 0.f, 0.f};

  for (int kt = 0; kt < K; kt += 64){
    #pragma unroll
    for (int i = 0; i < 4; i++){
      int c = tid + i * 256;
      int row = c >> 3, cc = (c & 7) * 8;
      glds16(A + (size_t)(m0 + row) * K + kt + cc, &As[c * 8]);
      glds16(B + (size_t)(n0 + row) * K + kt + cc, &Bs[c * 8]);
    }
    __syncthreads();
    #pragma unroll
    for (int ks = 0; ks < 2; ++ks){
      int ko = ks * 32 + lk;
      s8v av[4], bv[4];
      #pragma unroll
      for (int m = 0; m < 4; m++) av[m] = *(const s8v*)&As[(wm * 64 + m * 16 + lr) * 64 + ko];
      #pragma unroll
      for (int n = 0; n < 4; n++) bv[n] = *(const s8v*)&Bs[(wn * 64 + n * 16 + lr) * 64 + ko];
      #pragma unroll
      for (int m = 0; m < 4; m++)
        #pragma unroll
        for (int n = 0; n < 4; n++) mfma16(acc[m][n], av[m], bv[n]);
    }
    __syncthreads();
  }
  const int r0 = (lane >> 4) * 4;
  #pragma unroll
  for (int m = 0; m < 4; m++){
    #pragma unroll
    for (int n = 0; n < 4; n++){
      int col = n0 + wn * 64 + n * 16 + lr;
      float bc = bias[col];
      #pragma unroll
      for (int r = 0; r < 4; r++){
        int row = m0 + wm * 64 + m * 16 + r0 + r;
        float v = acc[m][n][r] + bc;
        if (RELU) v = fmaxf(v, 0.f);
        C[(size_t)row * N + col] = f2bf(v);
      }
    }
  }
}

// ---------- encoder ----------
union SMemE { u16 stage[32768]; float gx[4][32][17]; };

__global__ void __launch_bounds__(256, 1) k_encoder(const u16* __restrict__ Whh, const u16* __restrict__ Xih,
      u16* __restrict__ hbuf, u16* __restrict__ denc, u32* bar)
{
  __shared__ SMemE sm;
  const int nb = blockIdx.x, tid = threadIdx.x;
  const int lane = tid & 63, g = tid >> 6;
  const int jc = nb * 16;
  const int lr = lane & 15, lk = (lane >> 4) * 8;
  const int eb = tid >> 4, ejj = tid & 15;

  for (int i = tid; i < 512; i += 256){
    int b = i >> 4, jj = i & 15;
    stcc_u16(&hbuf[b * HH + jc + jj], 0);
  }
  float cr0 = 0.f, cr1 = 0.f;
  u32 epoch = 0;
  gbar(bar, 64, epoch);

  const u16* Wb = Whh + (size_t)(g * HH + jc + lr) * HH + lk;
  const int rb = (lane >> 4) * 4;
  for (int l = 0; l < LL; ++l){
    const u16* hb = hbuf + (l & 1) * (BB * HH);
    s8v ht[16];
    stage_issue(hb, ht);                      // coherent loads in flight
    // hoist Xih gate loads (plain, L2-cached) to overlap with staging+MFMA
    const u16* xr0 = Xih + ((size_t)(l * BB + eb)) * G4 + jc + ejj;
    const u16* xr1 = xr0 + (size_t)16 * G4;
    float xi0 = bf2f(xr0[0]), xf0 = bf2f(xr0[1024]), xg0 = bf2f(xr0[2048]), xo0 = bf2f(xr0[3072]);
    float xi1 = bf2f(xr1[0]), xf1 = bf2f(xr1[1024]), xg1 = bf2f(xr1[2048]), xo1 = bf2f(xr1[3072]);
    waitv0();
    stage_commit(ht, sm.stage);
    __syncthreads();
    f4v a0 = {0.f,0.f,0.f,0.f}, a1 = {0.f,0.f,0.f,0.f};
    #pragma unroll 8
    for (int ks = 0; ks < 32; ++ks){
      int cb = (lk + ks * 32) * 2;
      s8v va0 = ldsA(sm.stage, lr,      cb);
      s8v va1 = ldsA(sm.stage, lr + 16, cb);
      s8v vb  = *(const s8v*)(Wb + ks * 32);
      mfma16(a0, va0, vb);
      mfma16(a1, va1, vb);
    }
    __syncthreads();              // stage dead -> gx overlay
    #pragma unroll
    for (int r = 0; r < 4; r++){ sm.gx[g][rb + r][lr] = a0[r]; sm.gx[g][16 + rb + r][lr] = a1[r]; }
    __syncthreads();
    u16* ho = hbuf + ((l + 1) & 1) * (BB * HH);
    {
      float gi = sm.gx[0][eb][ejj] + xi0;
      float gf = sm.gx[1][eb][ejj] + xf0;
      float gg = sm.gx[2][eb][ejj] + xg0;
      float go = sm.gx[3][eb][ejj] + xo0;
      cr0 = sigf(gf) * cr0 + sigf(gi) * tanhf(gg);
      float h = sigf(go) * tanhf(cr0);
      u16 hv = f2bf(h);
      stcc_u16(&ho[eb * HH + jc + ejj], hv);
      stcc_u16(&denc[((size_t)(l * BB + eb)) * HH + jc + ejj], hv);
    }
    {
      int b2 = eb + 16;
      float gi = sm.gx[0][b2][ejj] + xi1;
      float gf = sm.gx[1][b2][ejj] + xf1;
      float gg = sm.gx[2][b2][ejj] + xg1;
      float go = sm.gx[3][b2][ejj] + xo1;
      cr1 = sigf(gf) * cr1 + sigf(gi) * tanhf(gg);
      float h = sigf(go) * tanhf(cr1);
      u16 hv = f2bf(h);
      stcc_u16(&ho[b2 * HH + jc + ejj], hv);
      stcc_u16(&denc[((size_t)(l * BB + b2)) * HH + jc + ejj], hv);
    }
    gbar(bar, 64, epoch);
  }
}

// ---------- decoder ----------
union SMemD {
  u16 stage[32768];
  float gx[4][32][17];
  struct { float ssc[128]; float swt[128]; } a;
};

__global__ void __launch_bounds__(256, 1) k_decoder(
    const u16* __restrict__ aproj, const u16* __restrict__ denc, const u16* __restrict__ obsp,
    const u16* __restrict__ W1c, const u16* __restrict__ W2w, const u16* __restrict__ WihL,
    const u16* __restrict__ WhhL, const float* __restrict__ blstm, const float* __restrict__ b2,
    const float* __restrict__ h0, const float* __restrict__ c0, const int* __restrict__ lens,
    float* __restrict__ hf, u16* __restrict__ hbuf, u16* __restrict__ ctxb,
    u16* __restrict__ mb, u16* __restrict__ xb, float* __restrict__ out, u32* bar)
{
  __shared__ SMemD sm;
  const int nb = blockIdx.x, tid = threadIdx.x;
  const int lane = tid & 63, w = tid >> 6;
  const int jc = nb * 16;
  const int lr = lane & 15, lk = (lane >> 4) * 8;
  const int eb = tid >> 4, ejj = tid & 15;
  const int rb = (lane >> 4) * 4;

  float cr0, cr1;
  {
    float hv0 = h0[eb * HH + jc + ejj];
    float hv1 = h0[(eb + 16) * HH + jc + ejj];
    stcc_f32(&hf[eb * HH + jc + ejj], hv0);
    stcc_f32(&hf[(eb + 16) * HH + jc + ejj], hv1);
    stcc_u16(&hbuf[eb * HH + jc + ejj], f2bf(hv0));
    stcc_u16(&hbuf[(eb + 16) * HH + jc + ejj], f2bf(hv1));
    cr0 = c0[eb * HH + jc + ejj];
    cr1 = c0[(eb + 16) * HH + jc + ejj];
  }
  u32 epoch = 0;
  gbar(bar, 64, epoch);

  s8v htmp[16];
  for (int t = 0; t < TT; ++t){
    // ---- Phase A: scores -> softmax -> ctx (blocks 0..31) ----
    if (nb < BB){
      const int b = nb;
      const int len = lens[b];
      f4v h4[4];
      const float* hp = hf + b * HH + lane * 16;
      #pragma unroll
      for (int i = 0; i < 4; i++) h4[i] = ldcc4f(hp + i * 4);
      waitv0();
      float hr[16];
      #pragma unroll
      for (int i = 0; i < 16; i++) hr[i] = h4[i >> 2][i & 3];
      for (int i = 0; i < 32; ++i){
        int l = w * 32 + i;
        const u16* ap = aproj + ((size_t)(l * BB + b)) * HH + lane * 16;
        s8v v0 = *(const s8v*)ap;
        s8v v1 = *(const s8v*)(ap + 8);
        float s = 0.f;
        #pragma unroll
        for (int k = 0; k < 8; k++) s += bf2f((u16)v0[k]) * hr[k];
        #pragma unroll
        for (int k = 0; k < 8; k++) s += bf2f((u16)v1[k]) * hr[8 + k];
        #pragma unroll
        for (int off = 32; off > 0; off >>= 1) s += __shfl_down(s, off);
        if (lane == 0){
          s *= SCALE_;
          if (l >= len && l != 0) s = -__builtin_inff();
          sm.a.ssc[l] = s;
        }
      }
      __syncthreads();
      if (w == 0){
        float x0 = sm.a.ssc[lane], x1 = sm.a.ssc[lane + 64];
        float mx = fmaxf(x0, x1);
        #pragma unroll
        for (int off = 32; off > 0; off >>= 1) mx = fmaxf(mx, __shfl_xor(mx, off));
        float e0 = __expf(x0 - mx), e1 = __expf(x1 - mx);
        float smv = e0 + e1;
        #pragma unroll
        for (int off = 32; off > 0; off >>= 1) smv += __shfl_xor(smv, off);
        float inv = 1.f / smv;
        sm.a.swt[lane] = e0 * inv;
        sm.a.swt[lane + 64] = e1 * inv;
      }
      __syncthreads();
      int hh = tid * 4;
      float a0 = 0, a1 = 0, a2 = 0, a3 = 0;
      #pragma unroll 4
      for (int l = 0; l < LL; ++l){
        float wv = sm.a.swt[l];
        const u16* dp = denc + ((size_t)(l * BB + b)) * HH + hh;
        s4v dv = *(const s4v*)dp;
        a0 += wv * bf2f((u16)dv[0]); a1 += wv * bf2f((u16)dv[1]);
        a2 += wv * bf2f((u16)dv[2]); a3 += wv * bf2f((u16)dv[3]);
      }
      u2v pk;
      pk[0] = ((u32)f2bf(a1) << 16) | f2bf(a0);
      pk[1] = ((u32)f2bf(a3) << 16) | f2bf(a2);
      stcc_2x32(ctxb + b * HH + hh, pk);
    }
    gbar(bar, 64, epoch);

    // ---- Phase B: m = relu(ctx @ W1c^T + obs_part[t]) ----
    {
      s8v ct[16];
      stage_issue(ctxb, ct);
      const int col0 = nb * 64 + w * 16;
      const int cc = col0 + lr;
      // hoist obsp loads
      float ov0[4], ov1[4];
      #pragma unroll
      for (int r = 0; r < 4; r++){
        ov0[r] = bf2f(obsp[((size_t)(t * BB + rb + r)) * G4 + cc]);
        ov1[r] = bf2f(obsp[((size_t)(t * BB + rb + r + 16)) * G4 + cc]);
      }
      waitv0();
      stage_commit(ct, sm.stage);
      __syncthreads();
      f4v a0 = {0.f,0.f,0.f,0.f}, a1 = {0.f,0.f,0.f,0.f};
      const u16* Bp = W1c + (size_t)(col0 + lr) * HH + lk;
      #pragma unroll 8
      for (int ks = 0; ks < 32; ++ks){
        int cb = (lk + ks * 32) * 2;
        s8v va0 = ldsA(sm.stage, lr,      cb);
        s8v va1 = ldsA(sm.stage, lr + 16, cb);
        s8v vb  = *(const s8v*)(Bp + ks * 32);
        mfma16(a0, va0, vb);
        mfma16(a1, va1, vb);
      }
      #pragma unroll
      for (int r = 0; r < 4; r++){
        int b = rb + r;
        stcc_u16(&mb[b * G4 + cc], f2bf(fmaxf(a0[r] + ov0[r], 0.f)));
        stcc_u16(&mb[(b + 16) * G4 + cc], f2bf(fmaxf(a1[r] + ov1[r], 0.f)));
      }
    }
    gbar(bar, 64, epoch);

    // ---- Phase C: x = relu(m @ W2^T + b2); waves K-split; 4 sequential chunks ----
    // (round-2 proven structure: one 16KB wave-private slice, no double-buffer)
    {
      f4v a0 = {0.f,0.f,0.f,0.f}, a1 = {0.f,0.f,0.f,0.f};
      u16* ldsw = sm.stage + w * 8192;       // per-wave 16KB slice
      const u16* Bp = W2w + (size_t)(jc + lr) * G4 + w * HH + lk;
      for (int c = 0; c < 4; ++c){
        s8v ct[16];
        stageC_issue(mb + w * HH + c * 256, ct, lane);
        waitv0();
        stageC_commit(ct, ldsw, lane);
        __syncthreads();
        #pragma unroll
        for (int ks = 0; ks < 8; ++ks){
          int cb = (lk + ks * 32) * 2;
          s8v va0 = ldsC(ldsw, lr,      cb);
          s8v va1 = ldsC(ldsw, lr + 16, cb);
          s8v vb  = *(const s8v*)(Bp + c * 256 + ks * 32);
          mfma16(a0, va0, vb);
          mfma16(a1, va1, vb);
        }
        __syncthreads();
      }
      #pragma unroll
      for (int r = 0; r < 4; r++){ sm.gx[w][rb + r][lr] = a0[r]; sm.gx[w][16 + rb + r][lr] = a1[r]; }
      __syncthreads();
      {
        float v0 = sm.gx[0][eb][ejj] + sm.gx[1][eb][ejj] + sm.gx[2][eb][ejj] + sm.gx[3][eb][ejj] + b2[jc + ejj];
        stcc_u16(&xb[eb * HH + jc + ejj], f2bf(fmaxf(v0, 0.f)));
        int b2e = eb + 16;
        float v1 = sm.gx[0][b2e][ejj] + sm.gx[1][b2e][ejj] + sm.gx[2][b2e][ejj] + sm.gx[3][b2e][ejj] + b2[jc + ejj];
        stcc_u16(&xb[b2e * HH + jc + ejj], f2bf(fmaxf(v1, 0.f)));
      }
      // prefetch h(t) tile for phase D (valid since end of D(t-1))
      stage_issue(hbuf + (t & 1) * (BB * HH), htmp);
    }
    gbar(bar, 64, epoch);

    // ---- Phase D: gates = x@WihL^T + h@WhhL^T + b; LSTM cell ----
    {
      s8v xt[16];
      stage_issue(xb, xt);
      waitv0();                               // xt + htmp both ready
      stage_commit(xt, sm.stage);
      __syncthreads();
      f4v a0 = {0.f,0.f,0.f,0.f}, a1 = {0.f,0.f,0.f,0.f};
      const u16* Bx = WihL + (size_t)(w * HH + jc + lr) * HH + lk;
      #pragma unroll 8
      for (int ks = 0; ks < 32; ++ks){
        int cb = (lk + ks * 32) * 2;
        s8v va0 = ldsA(sm.stage, lr,      cb);
        s8v va1 = ldsA(sm.stage, lr + 16, cb);
        s8v vb  = *(const s8v*)(Bx + ks * 32);
        mfma16(a0, va0, vb);
        mfma16(a1, va1, vb);
      }
      __syncthreads();
      stage_commit(htmp, sm.stage);
      __syncthreads();
      const u16* Bh = WhhL + (size_t)(w * HH + jc + lr) * HH + lk;
      #pragma unroll 8
      for (int ks = 0; ks < 32; ++ks){
        int cb = (lk + ks * 32) * 2;
        s8v va0 = ldsA(sm.stage, lr,      cb);
        s8v va1 = ldsA(sm.stage, lr + 16, cb);
        s8v vb  = *(const s8v*)(Bh + ks * 32);
        mfma16(a0, va0, vb);
        mfma16(a1, va1, vb);
      }
      __syncthreads();
      #pragma unroll
      for (int r = 0; r < 4; r++){ sm.gx[w][rb + r][lr] = a0[r]; sm.gx[w][16 + rb + r][lr] = a1[r]; }
      __syncthreads();
      u16* ho = hbuf + ((t + 1) & 1) * (BB * HH);
      {
        int col = jc + ejj;
        float gi = sm.gx[0][eb][ejj] + blstm[col];
        float gf = sm.gx[1][eb][ejj] + blstm[1024 + col];
        float gg = sm.gx[2][eb][ejj] + blstm[2048 + col];
        float go = sm.gx[3][eb][ejj] + blstm[3072 + col];
        cr0 = sigf(gf) * cr0 + sigf(gi) * tanhf(gg);
        float h = sigf(go) * tanhf(cr0);
        stcc_f32(&out[(size_t)t * (BB * HH) + eb * HH + col], h);
        stcc_f32(&hf[eb * HH + col], h);
        stcc_u16(&ho[eb * HH + col], f2bf(h));
        if (t == TT - 1){ stcc_f32(&out[1048576 + eb * HH + col], h); stcc_f32(&out[1081344 + eb * HH + col], cr0); }
        int b2e = eb + 16;
        float gi2 = sm.gx[0][b2e][ejj] + blstm[col];
        float gf2 = sm.gx[1][b2e][ejj] + blstm[1024 + col];
        float gg2 = sm.gx[2][b2e][ejj] + blstm[2048 + col];
        float go2 = sm.gx[3][b2e][ejj] + blstm[3072 + col];
        cr1 = sigf(gf2) * cr1 + sigf(gi2) * tanhf(gg2);
        float h2 = sigf(go2) * tanhf(cr1);
        stcc_f32(&out[(size_t)t * (BB * HH) + b2e * HH + col], h2);
        stcc_f32(&hf[b2e * HH + col], h2);
        stcc_u16(&ho[b2e * HH + col], f2bf(h2));
        if (t == TT - 1){ stcc_f32(&out[1048576 + b2e * HH + col], h2); stcc_f32(&out[1081344 + b2e * HH + col], cr1); }
      }
    }
    gbar(bar, 64, epoch);
  }
}

// ---------- workspace layout ----------
static constexpr size_t oWihE = 0;
static constexpr size_t oWhhE = oWihE + 4194304;
static constexpr size_t oAttnW= oWhhE + 8388608;
static constexpr size_t oW1C  = oAttnW+ 2097152;
static constexpr size_t oW1O  = oW1C  + 8388608;
static constexpr size_t oW2   = oW1O  + 4194304;
static constexpr size_t oWihL = oW2   + 8388608;
static constexpr size_t oWhhL = oWihL + 8388608;
static constexpr size_t oBEnc = oWhhL + 8388608;
static constexpr size_t oBL   = oBEnc + 16384;
static constexpr size_t oDemoT= oBL   + 16384;
static constexpr size_t oObsB = oDemoT+ 4194304;
static constexpr size_t oXih  = oObsB + 1048576;
static constexpr size_t oObsP = oXih  + 33554432;
static constexpr size_t oDEnc = oObsP + 8388608;
static constexpr size_t oAPrj = oDEnc + 8388608;
static constexpr size_t oHF   = oAPrj + 8388608;
static constexpr size_t oHB   = oHF   + 131072;
static constexpr size_t oCtx  = oHB   + 131072;
static constexpr size_t oMB   = oCtx  + 65536;
static constexpr size_t oXB   = oMB   + 262144;
static constexpr size_t oBar  = oXB   + 65536;

extern "C" void kernel_launch(void* const* d_in, const int* in_sizes, int n_in,
                              void* d_out, int out_size, void* d_ws, size_t ws_size,
                              hipStream_t stream)
{
  const float* demo = (const float*)d_in[0];
  const int*   lens = (const int*)  d_in[1];
  const float* obs  = (const float*)d_in[2];
  const float* h0   = (const float*)d_in[3];
  const float* c0   = (const float*)d_in[4];
  const float* eWih = (const float*)d_in[5];
  const float* eWhh = (const float*)d_in[6];
  const float* eBih = (const float*)d_in[7];
  const float* eBhh = (const float*)d_in[8];
  const float* aW   = (const float*)d_in[9];
  const float* aB   = (const float*)d_in[10];
  const float* W1   = (const float*)d_in[11];
  const float* B1   = (const float*)d_in[12];
  const float* W2   = (const float*)d_in[13];
  const float* B2   = (const float*)d_in[14];
  const float* lWih = (const float*)d_in[15];
  const float* lWhh = (const float*)d_in[16];
  const float* lBih = (const float*)d_in[17];
  const float* lBhh = (const float*)d_in[18];

  char* ws = (char*)d_ws;
  u16*  WihE = (u16*)(ws + oWihE);
  u16*  WhhE = (u16*)(ws + oWhhE);
  u16*  AttnW= (u16*)(ws + oAttnW);
  u16*  W1C  = (u16*)(ws + oW1C);
  u16*  W1O  = (u16*)(ws + oW1O);
  u16*  W2w  = (u16*)(ws + oW2);
  u16*  WihL = (u16*)(ws + oWihL);
  u16*  WhhL = (u16*)(ws + oWhhL);
  float* BEnc= (float*)(ws + oBEnc);
  float* BL  = (float*)(ws + oBL);
  u16*  DemoT= (u16*)(ws + oDemoT);
  u16*  ObsB = (u16*)(ws + oObsB);
  u16*  Xih  = (u16*)(ws + oXih);
  u16*  ObsP = (u16*)(ws + oObsP);
  u16*  DEnc = (u16*)(ws + oDEnc);
  u16*  APrj = (u16*)(ws + oAPrj);
  float* HF  = (float*)(ws + oHF);
  u16*  HB   = (u16*)(ws + oHB);
  u16*  Ctx  = (u16*)(ws + oCtx);
  u16*  MB   = (u16*)(ws + oMB);
  u16*  XB   = (u16*)(ws + oXB);
  u32*  Bar  = (u32*)(ws + oBar);

  k_convert<<<1024, 256, 0, stream>>>(eWih, WihE, G4 * FF);
  k_convert<<<1024, 256, 0, stream>>>(eWhh, WhhE, G4 * HH);
  k_convert<<<512,  256, 0, stream>>>(aW,   AttnW, HH * HH);
  k_split_w1<<<1024, 256, 0, stream>>>(W1, W1C, W1O);
  k_convert<<<1024, 256, 0, stream>>>(W2,   W2w,  HH * G4);
  k_convert<<<1024, 256, 0, stream>>>(lWih, WihL, G4 * HH);
  k_convert<<<1024, 256, 0, stream>>>(lWhh, WhhL, G4 * HH);
  k_addb<<<16, 256, 0, stream>>>(eBih, eBhh, BEnc, G4);
  k_addb<<<16, 256, 0, stream>>>(lBih, lBhh, BL, G4);
  k_demo_t<<<1024, 256, 0, stream>>>(demo, DemoT);
  k_convert<<<512, 256, 0, stream>>>(obs, ObsB, TT * BB * FF);
  hipMemsetAsync(Bar, 0, 256, stream);

  {
    dim3 g(LL * BB / 128, G4 / 128);
    k_gemm_bt<0><<<g, 256, 0, stream>>>(DemoT, WihE, BEnc, Xih, LL * BB, G4, FF);
  }
  {
    dim3 g(TT * BB / 128, G4 / 128);
    k_gemm_bt<0><<<g, 256, 0, stream>>>(ObsB, W1O, B1, ObsP, TT * BB, G4, FF);
  }

  k_encoder<<<64, 256, 0, stream>>>(WhhE, Xih, HB, DEnc, Bar);

  {
    dim3 g(LL * BB / 128, HH / 128);
    k_gemm_bt<0><<<g, 256, 0, stream>>>(DEnc, AttnW, aB, APrj, LL * BB, HH, HH);
  }

  k_decoder<<<64, 256, 0, stream>>>(APrj, DEnc, ObsP, W1C, W2w, WihL, WhhL,
                                    BL, B2, h0, c0, lens,
                                    HF, HB, Ctx, MB, XB, (float*)d_out, Bar + 16);
}

// Round 5
// 3231.223 us; speedup vs baseline: 1.7829x; 1.3362x over previous
//
#include <hip/hip_runtime.h>

typedef unsigned short u16;
typedef unsigned int   u32;
typedef short s8v __attribute__((ext_vector_type(8)));
typedef short s4v __attribute__((ext_vector_type(4)));
typedef float f4v __attribute__((ext_vector_type(4)));
typedef u32   u2v __attribute__((ext_vector_type(2)));

// Problem constants
#define TT 32
#define BB 32
#define LL 128
#define FF 512
#define HH 1024
#define G4 4096
#define SCALE_ 0.08838834764831845f   // 1/sqrt(128)

// ---------- helpers ----------
__device__ __forceinline__ u16 f2bf(float f){
  u32 u = __float_as_uint(f);
  u32 r = u + 0x7fffu + ((u >> 16) & 1u);   // RNE
  return (u16)(r >> 16);
}
__device__ __forceinline__ float bf2f(u16 s){ return __uint_as_float(((u32)s) << 16); }
__device__ __forceinline__ float sigf(float x){ return 1.f / (1.f + __expf(-x)); }

__device__ __forceinline__ void mfma16(f4v& d, s8v a, s8v b){
  asm("v_mfma_f32_16x16x32_bf16 %0, %1, %2, %0" : "+v"(d) : "v"(a), "v"(b));
}

typedef __attribute__((address_space(3))) u32 as3u32;
typedef __attribute__((address_space(1))) u32 as1u32;
__device__ __forceinline__ void glds16(const u16* g, u16* l){
  __builtin_amdgcn_global_load_lds((const as1u32*)g, (as3u32*)l, 16, 0, 0);
}

// ---- producer stores: write-through to LLC (coherent point), no dirty L2 ----
__device__ __forceinline__ void stcc_u16(u16* p, u16 v){
  u32 vv = v;
  asm volatile("global_store_short %0, %1, off sc0 sc1" :: "v"(p), "v"(vv) : "memory");
}
__device__ __forceinline__ void stcc_f32(float* p, float v){
  asm volatile("global_store_dword %0, %1, off sc0 sc1" :: "v"(p), "v"(v) : "memory");
}
__device__ __forceinline__ void stcc_2x32(void* p, u2v v){
  asm volatile("global_store_dwordx2 %0, %1, off sc0 sc1" :: "v"(p), "v"(v) : "memory");
}
__device__ __forceinline__ u32 poll_ld(const u32* p){
  u32 v;
  asm volatile("global_load_dword %0, %1, off sc0 sc1\n\ts_waitcnt vmcnt(0)"
               : "=v"(v) : "v"(p) : "memory");
  return v;
}

// grid barrier: vmcnt(0) drains producer sc0sc1 stores (release);
// sc0sc1 poll is the acquire. No cache maintenance.
// Consumers use PLAIN cached loads of write-once (per launch) rotated buffers:
// address never read before its single write -> no stale line possible; values
// are replay-invariant so cross-launch L2 hits are bit-identical anyway.
__device__ __forceinline__ void gbar(u32* cnt, u32 nblk, u32& epoch){
  asm volatile("s_waitcnt vmcnt(0)" ::: "memory");
  __syncthreads();
  ++epoch;
  if (threadIdx.x == 0){
    atomicAdd(cnt, 1u);
    u32 target = epoch * nblk;
    while (poll_ld(cnt) < target) __builtin_amdgcn_s_sleep(1);
  }
  __syncthreads();
}

// ---------- staging: [32][1024] u16 -> LDS, XOR swizzle (byte ^= (row&15)<<4) ----------
// consumer reads are PLAIN (L1+L2 cached; L2 dedups the 8-blocks-per-XCD broadcast)
__device__ __forceinline__ void stage_issue(const u16* __restrict__ src, s8v* tmp){
  const int tid = threadIdx.x;
  const int row = tid >> 3, s0 = tid & 7;
  const u16* p = src + row * HH + s0 * 8;
  #pragma unroll
  for (int i = 0; i < 16; i++) tmp[i] = *(const s8v*)(p + i * 64);
}
__device__ __forceinline__ void stage_commit(const s8v* tmp, u16* lds){
  const int tid = threadIdx.x;
  const int row = tid >> 3, s0 = tid & 7;
  char* base = (char*)lds + (row << 11);
  u32 x = (u32)(row & 15) << 4;
  #pragma unroll
  for (int i = 0; i < 16; i++){
    u32 cb = (u32)(s0 + 8 * i) << 4;
    *(s8v*)(base + (cb ^ x)) = tmp[i];
  }
}
__device__ __forceinline__ s8v ldsA(const u16* lds, int row, int cb){
  return *(const s8v*)((const char*)lds + (row << 11) + (cb ^ ((row & 15) << 4)));
}
// phase-C per-wave [32][256] slice (16KB), row stride 512B
__device__ __forceinline__ void stageC_issue(const u16* __restrict__ src, s8v* tmp, int lane){
  const int row = lane >> 1, s0 = lane & 1;
  const u16* p = src + row * G4 + s0 * 8;
  #pragma unroll
  for (int i = 0; i < 16; i++) tmp[i] = *(const s8v*)(p + i * 16);
}
__device__ __forceinline__ void stageC_commit(const s8v* tmp, u16* ldsw, int lane){
  const int row = lane >> 1, s0 = lane & 1;
  char* base = (char*)ldsw + (row << 9);
  u32 x = (u32)(row & 15) << 4;
  #pragma unroll
  for (int i = 0; i < 16; i++){
    u32 cb = (u32)(s0 + 2 * i) << 4;
    *(s8v*)(base + (cb ^ x)) = tmp[i];
  }
}
__device__ __forceinline__ s8v ldsC(const u16* ldsw, int row, int cb){
  return *(const s8v*)((const char*)ldsw + (row << 9) + (cb ^ ((row & 15) << 4)));
}

// ---------- prep kernels ----------
__global__ void k_convert(const float* __restrict__ src, u16* __restrict__ dst, int n){
  int i = blockIdx.x * blockDim.x + threadIdx.x;
  int st = gridDim.x * blockDim.x;
  for (; i < n; i += st) dst[i] = f2bf(src[i]);
}
__global__ void k_split_w1(const float* __restrict__ w1, u16* __restrict__ w1c, u16* __restrict__ w1o){
  int i = blockIdx.x * blockDim.x + threadIdx.x;
  int st = gridDim.x * blockDim.x;
  const int n = G4 * (FF + HH);
  for (; i < n; i += st){
    int j = i / 1536, k = i - j * 1536;
    u16 v = f2bf(w1[i]);
    if (k < HH) w1c[j * HH + k] = v;
    else        w1o[j * FF + (k - HH)] = v;
  }
}
__global__ void k_addb(const float* __restrict__ a, const float* __restrict__ b,
                       float* __restrict__ o, int n){
  int i = blockIdx.x * blockDim.x + threadIdx.x;
  int st = gridDim.x * blockDim.x;
  for (; i < n; i += st) o[i] = a[i] + b[i];
}
__global__ void k_demo_t(const float* __restrict__ d, u16* __restrict__ o){
  const int n = LL * BB * FF;
  int i = blockIdx.x * blockDim.x + threadIdx.x;
  int st = gridDim.x * blockDim.x;
  for (; i < n; i += st){
    int f = i & 511;
    int row = i >> 9;
    int l = row >> 5, b = row & 31;
    o[i] = f2bf(d[(size_t)b * (LL * FF) + l * FF + f]);
  }
}

// ---------- generic GEMM (unchanged) ----------
template<int RELU>
__global__ void __launch_bounds__(256) k_gemm_bt(const u16* __restrict__ A, const u16* __restrict__ B,
        const float* __restrict__ bias, u16* __restrict__ C, int M, int N, int K)
{
  __shared__ u16 As[128 * 64];
  __shared__ u16 Bs[128 * 64];
  const int tid = threadIdx.x;
  const int lane = tid & 63, wave = tid >> 6;
  const int m0 = blockIdx.x * 128, n0 = blockIdx.y * 128;
  const int wm = wave >> 1, wn = wave & 1;
  const int lr = lane & 15, lk = (lane >> 4) * 8;
  f4v acc[4][4];
  #pragma unroll
  for (int i = 0; i < 4; i++)
    #pragma unroll
    for (int j = 0; j < 4; j++) acc[i][j] = f4v{0.f, 0.f, 0.f, 0.f};

  for (int kt = 0; kt < K; kt += 64){
    #pragma unroll
    for (int i = 0; i < 4; i++){
      int c = tid + i * 256;
      int row = c >> 3, cc = (c & 7) * 8;
      glds16(A + (size_t)(m0 + row) * K + kt + cc, &As[c * 8]);
      glds16(B + (size_t)(n0 + row) * K + kt + cc, &Bs[c * 8]);
    }
    __syncthreads();
    #pragma unroll
    for (int ks = 0; ks < 2; ++ks){
      int ko = ks * 32 + lk;
      s8v av[4], bv[4];
      #pragma unroll
      for (int m = 0; m < 4; m++) av[m] = *(const s8v*)&As[(wm * 64 + m * 16 + lr) * 64 + ko];
      #pragma unroll
      for (int n = 0; n < 4; n++) bv[n] = *(const s8v*)&Bs[(wn * 64 + n * 16 + lr) * 64 + ko];
      #pragma unroll
      for (int m = 0; m < 4; m++)
        #pragma unroll
        for (int n = 0; n < 4; n++) mfma16(acc[m][n], av[m], bv[n]);
    }
    __syncthreads();
  }
  const int r0 = (lane >> 4) * 4;
  #pragma unroll
  for (int m = 0; m < 4; m++){
    #pragma unroll
    for (int n = 0; n < 4; n++){
      int col = n0 + wn * 64 + n * 16 + lr;
      float bc = bias[col];
      #pragma unroll
      for (int r = 0; r < 4; r++){
        int row = m0 + wm * 64 + m * 16 + r0 + r;
        float v = acc[m][n][r] + bc;
        if (RELU) v = fmaxf(v, 0.f);
        C[(size_t)row * N + col] = f2bf(v);
      }
    }
  }
}

// ---------- encoder: h-chain lives in denc[l] (write-once per l) ----------
union SMemE { u16 stage[32768]; float gx[4][32][17]; };

__global__ void __launch_bounds__(256, 1) k_encoder(const u16* __restrict__ Whh, const u16* __restrict__ Xih,
      u16* __restrict__ zslot, u16* __restrict__ denc, u32* bar)
{
  __shared__ SMemE sm;
  const int nb = blockIdx.x, tid = threadIdx.x;
  const int lane = tid & 63, g = tid >> 6;
  const int jc = nb * 16;
  const int lr = lane & 15, lk = (lane >> 4) * 8;
  const int eb = tid >> 4, ejj = tid & 15;

  for (int i = tid; i < 512; i += 256){     // zero slot (h(-1) = 0), own cols
    int b = i >> 4, jj = i & 15;
    stcc_u16(&zslot[b * HH + jc + jj], 0);
  }
  float cr0 = 0.f, cr1 = 0.f;
  u32 epoch = 0;
  gbar(bar, 64, epoch);

  const u16* Wb = Whh + (size_t)(g * HH + jc + lr) * HH + lk;
  const int rb = (lane >> 4) * 4;
  for (int l = 0; l < LL; ++l){
    const u16* hb = (l == 0) ? zslot : (denc + (size_t)(l - 1) * (BB * HH));
    s8v ht[16];
    stage_issue(hb, ht);                    // plain cached loads (L2 dedup)
    const u16* xr0 = Xih + ((size_t)(l * BB + eb)) * G4 + jc + ejj;
    const u16* xr1 = xr0 + (size_t)16 * G4;
    float xi0 = bf2f(xr0[0]), xf0 = bf2f(xr0[1024]), xg0 = bf2f(xr0[2048]), xo0 = bf2f(xr0[3072]);
    float xi1 = bf2f(xr1[0]), xf1 = bf2f(xr1[1024]), xg1 = bf2f(xr1[2048]), xo1 = bf2f(xr1[3072]);
    stage_commit(ht, sm.stage);
    __syncthreads();
    f4v a0 = {0.f,0.f,0.f,0.f}, a1 = {0.f,0.f,0.f,0.f};
    #pragma unroll 8
    for (int ks = 0; ks < 32; ++ks){
      int cb = (lk + ks * 32) * 2;
      s8v va0 = ldsA(sm.stage, lr,      cb);
      s8v va1 = ldsA(sm.stage, lr + 16, cb);
      s8v vb  = *(const s8v*)(Wb + ks * 32);
      mfma16(a0, va0, vb);
      mfma16(a1, va1, vb);
    }
    __syncthreads();
    #pragma unroll
    for (int r = 0; r < 4; r++){ sm.gx[g][rb + r][lr] = a0[r]; sm.gx[g][16 + rb + r][lr] = a1[r]; }
    __syncthreads();
    u16* ho = denc + (size_t)l * (BB * HH);
    {
      float gi = sm.gx[0][eb][ejj] + xi0;
      float gf = sm.gx[1][eb][ejj] + xf0;
      float gg = sm.gx[2][eb][ejj] + xg0;
      float go = sm.gx[3][eb][ejj] + xo0;
      cr0 = sigf(gf) * cr0 + sigf(gi) * tanhf(gg);
      float h = sigf(go) * tanhf(cr0);
      stcc_u16(&ho[eb * HH + jc + ejj], f2bf(h));
    }
    {
      int b2 = eb + 16;
      float gi = sm.gx[0][b2][ejj] + xi1;
      float gf = sm.gx[1][b2][ejj] + xf1;
      float gg = sm.gx[2][b2][ejj] + xg1;
      float go = sm.gx[3][b2][ejj] + xo1;
      cr1 = sigf(gf) * cr1 + sigf(gi) * tanhf(gg);
      float h = sigf(go) * tanhf(cr1);
      stcc_u16(&ho[b2 * HH + jc + ejj], f2bf(h));
    }
    gbar(bar, 64, epoch);
  }
}

// ---------- decoder: all cross-block activations rotated by t ----------
union SMemD {
  u16 stage[32768];
  float gx[4][32][17];
  struct { float ssc[128]; float swt[128]; } a;
};

__global__ void __launch_bounds__(256, 1) k_decoder(
    const u16* __restrict__ aproj, const u16* __restrict__ denc, const u16* __restrict__ obsp,
    const u16* __restrict__ W1c, const u16* __restrict__ W2w, const u16* __restrict__ WihL,
    const u16* __restrict__ WhhL, const float* __restrict__ blstm, const float* __restrict__ b2,
    const float* __restrict__ h0, const float* __restrict__ c0, const int* __restrict__ lens,
    float* __restrict__ hfR, u16* __restrict__ hbR, u16* __restrict__ ctxR,
    u16* __restrict__ mbR, u16* __restrict__ xbR, float* __restrict__ out, u32* bar)
{
  __shared__ SMemD sm;
  const int nb = blockIdx.x, tid = threadIdx.x;
  const int lane = tid & 63, w = tid >> 6;
  const int jc = nb * 16;
  const int lr = lane & 15, lk = (lane >> 4) * 8;
  const int eb = tid >> 4, ejj = tid & 15;
  const int rb = (lane >> 4) * 4;

  float cr0, cr1;
  {
    float hv0 = h0[eb * HH + jc + ejj];
    float hv1 = h0[(eb + 16) * HH + jc + ejj];
    stcc_f32(&hfR[eb * HH + jc + ejj], hv0);
    stcc_f32(&hfR[(eb + 16) * HH + jc + ejj], hv1);
    stcc_u16(&hbR[eb * HH + jc + ejj], f2bf(hv0));
    stcc_u16(&hbR[(eb + 16) * HH + jc + ejj], f2bf(hv1));
    cr0 = c0[eb * HH + jc + ejj];
    cr1 = c0[(eb + 16) * HH + jc + ejj];
  }
  u32 epoch = 0;
  gbar(bar, 64, epoch);

  s8v htmp[16];
  for (int t = 0; t < TT; ++t){
    const u16* ctxS = ctxR + (size_t)t * (BB * HH);
    const u16* mbS  = mbR  + (size_t)t * (BB * G4);
    const u16* xbS  = xbR  + (size_t)t * (BB * HH);
    const u16* hbS  = hbR  + (size_t)t * (BB * HH);
    const float* hfS= hfR  + (size_t)t * (BB * HH);

    // ---- Phase A: scores -> softmax -> ctx (blocks 0..31) ----
    if (nb < BB){
      const int b = nb;
      const int len = lens[b];
      float hr[16];
      const float* hp = hfS + b * HH + lane * 16;
      #pragma unroll
      for (int i = 0; i < 16; i++) hr[i] = hp[i];
      for (int i = 0; i < 32; ++i){
        int l = w * 32 + i;
        const u16* ap = aproj + ((size_t)(l * BB + b)) * HH + lane * 16;
        s8v v0 = *(const s8v*)ap;
        s8v v1 = *(const s8v*)(ap + 8);
        float s = 0.f;
        #pragma unroll
        for (int k = 0; k < 8; k++) s += bf2f((u16)v0[k]) * hr[k];
        #pragma unroll
        for (int k = 0; k < 8; k++) s += bf2f((u16)v1[k]) * hr[8 + k];
        #pragma unroll
        for (int off = 32; off > 0; off >>= 1) s += __shfl_down(s, off);
        if (lane == 0){
          s *= SCALE_;
          if (l >= len && l != 0) s = -__builtin_inff();
          sm.a.ssc[l] = s;
        }
      }
      __syncthreads();
      if (w == 0){
        float x0 = sm.a.ssc[lane], x1 = sm.a.ssc[lane + 64];
        float mx = fmaxf(x0, x1);
        #pragma unroll
        for (int off = 32; off > 0; off >>= 1) mx = fmaxf(mx, __shfl_xor(mx, off));
        float e0 = __expf(x0 - mx), e1 = __expf(x1 - mx);
        float smv = e0 + e1;
        #pragma unroll
        for (int off = 32; off > 0; off >>= 1) smv += __shfl_xor(smv, off);
        float inv = 1.f / smv;
        sm.a.swt[lane] = e0 * inv;
        sm.a.swt[lane + 64] = e1 * inv;
      }
      __syncthreads();
      int hh = tid * 4;
      float a0 = 0, a1 = 0, a2 = 0, a3 = 0;
      #pragma unroll 4
      for (int l = 0; l < LL; ++l){
        float wv = sm.a.swt[l];
        const u16* dp = denc + ((size_t)(l * BB + b)) * HH + hh;
        s4v dv = *(const s4v*)dp;
        a0 += wv * bf2f((u16)dv[0]); a1 += wv * bf2f((u16)dv[1]);
        a2 += wv * bf2f((u16)dv[2]); a3 += wv * bf2f((u16)dv[3]);
      }
      u2v pk;
      pk[0] = ((u32)f2bf(a1) << 16) | f2bf(a0);
      pk[1] = ((u32)f2bf(a3) << 16) | f2bf(a2);
      stcc_2x32((void*)(ctxS + b * HH + hh), pk);
    }
    gbar(bar, 64, epoch);

    // ---- Phase B: m = relu(ctx @ W1c^T + obs_part[t]) ----
    {
      s8v ct[16];
      stage_issue(ctxS, ct);
      const int col0 = nb * 64 + w * 16;
      const int cc = col0 + lr;
      float ov0[4], ov1[4];
      #pragma unroll
      for (int r = 0; r < 4; r++){
        ov0[r] = bf2f(obsp[((size_t)(t * BB + rb + r)) * G4 + cc]);
        ov1[r] = bf2f(obsp[((size_t)(t * BB + rb + r + 16)) * G4 + cc]);
      }
      stage_commit(ct, sm.stage);
      __syncthreads();
      f4v a0 = {0.f,0.f,0.f,0.f}, a1 = {0.f,0.f,0.f,0.f};
      const u16* Bp = W1c + (size_t)(col0 + lr) * HH + lk;
      #pragma unroll 8
      for (int ks = 0; ks < 32; ++ks){
        int cb = (lk + ks * 32) * 2;
        s8v va0 = ldsA(sm.stage, lr,      cb);
        s8v va1 = ldsA(sm.stage, lr + 16, cb);
        s8v vb  = *(const s8v*)(Bp + ks * 32);
        mfma16(a0, va0, vb);
        mfma16(a1, va1, vb);
      }
      #pragma unroll
      for (int r = 0; r < 4; r++){
        int b = rb + r;
        stcc_u16((u16*)&mbS[b * G4 + cc], f2bf(fmaxf(a0[r] + ov0[r], 0.f)));
        stcc_u16((u16*)&mbS[(b + 16) * G4 + cc], f2bf(fmaxf(a1[r] + ov1[r], 0.f)));
      }
    }
    gbar(bar, 64, epoch);

    // ---- Phase C: x = relu(m @ W2^T + b2); waves K-split; 4 sequential chunks ----
    {
      f4v a0 = {0.f,0.f,0.f,0.f}, a1 = {0.f,0.f,0.f,0.f};
      u16* ldsw = sm.stage + w * 8192;       // per-wave 16KB slice
      const u16* Bp = W2w + (size_t)(jc + lr) * G4 + w * HH + lk;
      for (int c = 0; c < 4; ++c){
        s8v ct[16];
        stageC_issue(mbS + w * HH + c * 256, ct, lane);
        stageC_commit(ct, ldsw, lane);
        __syncthreads();
        #pragma unroll
        for (int ks = 0; ks < 8; ++ks){
          int cb = (lk + ks * 32) * 2;
          s8v va0 = ldsC(ldsw, lr,      cb);
          s8v va1 = ldsC(ldsw, lr + 16, cb);
          s8v vb  = *(const s8v*)(Bp + c * 256 + ks * 32);
          mfma16(a0, va0, vb);
          mfma16(a1, va1, vb);
        }
        __syncthreads();
      }
      #pragma unroll
      for (int r = 0; r < 4; r++){ sm.gx[w][rb + r][lr] = a0[r]; sm.gx[w][16 + rb + r][lr] = a1[r]; }
      __syncthreads();
      {
        float v0 = sm.gx[0][eb][ejj] + sm.gx[1][eb][ejj] + sm.gx[2][eb][ejj] + sm.gx[3][eb][ejj] + b2[jc + ejj];
        stcc_u16((u16*)&xbS[eb * HH + jc + ejj], f2bf(fmaxf(v0, 0.f)));
        int b2e = eb + 16;
        float v1 = sm.gx[0][b2e][ejj] + sm.gx[1][b2e][ejj] + sm.gx[2][b2e][ejj] + sm.gx[3][b2e][ejj] + b2[jc + ejj];
        stcc_u16((u16*)&xbS[b2e * HH + jc + ejj], f2bf(fmaxf(v1, 0.f)));
      }
      // prefetch h(t) tile for phase D (slot t written in D(t-1), plain cached)
      stage_issue(hbS, htmp);
    }
    gbar(bar, 64, epoch);

    // ---- Phase D: gates = x@WihL^T + h@WhhL^T + b; LSTM cell ----
    {
      s8v xt[16];
      stage_issue(xbS, xt);
      stage_commit(xt, sm.stage);
      __syncthreads();
      f4v a0 = {0.f,0.f,0.f,0.f}, a1 = {0.f,0.f,0.f,0.f};
      const u16* Bx = WihL + (size_t)(w * HH + jc + lr) * HH + lk;
      #pragma unroll 8
      for (int ks = 0; ks < 32; ++ks){
        int cb = (lk + ks * 32) * 2;
        s8v va0 = ldsA(sm.stage, lr,      cb);
        s8v va1 = ldsA(sm.stage, lr + 16, cb);
        s8v vb  = *(const s8v*)(Bx + ks * 32);
        mfma16(a0, va0, vb);
        mfma16(a1, va1, vb);
      }
      __syncthreads();
      stage_commit(htmp, sm.stage);
      __syncthreads();
      const u16* Bh = WhhL + (size_t)(w * HH + jc + lr) * HH + lk;
      #pragma unroll 8
      for (int ks = 0; ks < 32; ++ks){
        int cb = (lk + ks * 32) * 2;
        s8v va0 = ldsA(sm.stage, lr,      cb);
        s8v va1 = ldsA(sm.stage, lr + 16, cb);
        s8v vb  = *(const s8v*)(Bh + ks * 32);
        mfma16(a0, va0, vb);
        mfma16(a1, va1, vb);
      }
      __syncthreads();
      #pragma unroll
      for (int r = 0; r < 4; r++){ sm.gx[w][rb + r][lr] = a0[r]; sm.gx[w][16 + rb + r][lr] = a1[r]; }
      __syncthreads();
      u16* ho = hbR + (size_t)(t + 1) * (BB * HH);
      float* hfo = hfR + (size_t)(t + 1) * (BB * HH);
      {
        int col = jc + ejj;
        float gi = sm.gx[0][eb][ejj] + blstm[col];
        float gf = sm.gx[1][eb][ejj] + blstm[1024 + col];
        float gg = sm.gx[2][eb][ejj] + blstm[2048 + col];
        float go = sm.gx[3][eb][ejj] + blstm[3072 + col];
        cr0 = sigf(gf) * cr0 + sigf(gi) * tanhf(gg);
        float h = sigf(go) * tanhf(cr0);
        stcc_f32(&out[(size_t)t * (BB * HH) + eb * HH + col], h);
        stcc_f32(&hfo[eb * HH + col], h);
        stcc_u16(&ho[eb * HH + col], f2bf(h));
        if (t == TT - 1){ stcc_f32(&out[1048576 + eb * HH + col], h); stcc_f32(&out[1081344 + eb * HH + col], cr0); }
        int b2e = eb + 16;
        float gi2 = sm.gx[0][b2e][ejj] + blstm[col];
        float gf2 = sm.gx[1][b2e][ejj] + blstm[1024 + col];
        float gg2 = sm.gx[2][b2e][ejj] + blstm[2048 + col];
        float go2 = sm.gx[3][b2e][ejj] + blstm[3072 + col];
        cr1 = sigf(gf2) * cr1 + sigf(gi2) * tanhf(gg2);
        float h2 = sigf(go2) * tanhf(cr1);
        stcc_f32(&out[(size_t)t * (BB * HH) + b2e * HH + col], h2);
        stcc_f32(&hfo[b2e * HH + col], h2);
        stcc_u16(&ho[b2e * HH + col], f2bf(h2));
        if (t == TT - 1){ stcc_f32(&out[1048576 + b2e * HH + col], h2); stcc_f32(&out[1081344 + b2e * HH + col], cr1); }
      }
    }
    gbar(bar, 64, epoch);
  }
}

// ---------- workspace layout (bytes) ----------
static constexpr size_t oWihE = 0;                       // 4,194,304
static constexpr size_t oWhhE = oWihE + 4194304;         // 8,388,608
static constexpr size_t oAttnW= oWhhE + 8388608;         // 2,097,152
static constexpr size_t oW1C  = oAttnW+ 2097152;         // 8,388,608
static constexpr size_t oW1O  = oW1C  + 8388608;         // 4,194,304
static constexpr size_t oW2   = oW1O  + 4194304;         // 8,388,608
static constexpr size_t oWihL = oW2   + 8388608;         // 8,388,608
static constexpr size_t oWhhL = oWihL + 8388608;         // 8,388,608
static constexpr size_t oBEnc = oWhhL + 8388608;         // 16,384
static constexpr size_t oBL   = oBEnc + 16384;           // 16,384
static constexpr size_t oDemoT= oBL   + 16384;           // 4,194,304
static constexpr size_t oObsB = oDemoT+ 4194304;         // 1,048,576
static constexpr size_t oXih  = oObsB + 1048576;         // 33,554,432
static constexpr size_t oObsP = oXih  + 33554432;        // 8,388,608
static constexpr size_t oDEnc = oObsP + 8388608;         // 8,388,608 (128 slots x 64KB, h-chain)
static constexpr size_t oAPrj = oDEnc + 8388608;         // 8,388,608
static constexpr size_t oZE   = oAPrj + 8388608;         // 65,536   (encoder zero h)
static constexpr size_t oHFR  = oZE   + 65536;           // 33 x 131072 = 4,325,376
static constexpr size_t oHBR  = oHFR  + 4325376;         // 33 x 65536  = 2,162,688
static constexpr size_t oCtxR = oHBR  + 2162688;         // 32 x 65536  = 2,097,152
static constexpr size_t oMBR  = oCtxR + 2097152;         // 32 x 262144 = 8,388,608
static constexpr size_t oXBR  = oMBR  + 8388608;         // 32 x 65536  = 2,097,152
static constexpr size_t oBar  = oXBR  + 2097152;         // 256
// total ~135.7 MB

extern "C" void kernel_launch(void* const* d_in, const int* in_sizes, int n_in,
                              void* d_out, int out_size, void* d_ws, size_t ws_size,
                              hipStream_t stream)
{
  const float* demo = (const float*)d_in[0];
  const int*   lens = (const int*)  d_in[1];
  const float* obs  = (const float*)d_in[2];
  const float* h0   = (const float*)d_in[3];
  const float* c0   = (const float*)d_in[4];
  const float* eWih = (const float*)d_in[5];
  const float* eWhh = (const float*)d_in[6];
  const float* eBih = (const float*)d_in[7];
  const float* eBhh = (const float*)d_in[8];
  const float* aW   = (const float*)d_in[9];
  const float* aB   = (const float*)d_in[10];
  const float* W1   = (const float*)d_in[11];
  const float* B1   = (const float*)d_in[12];
  const float* W2   = (const float*)d_in[13];
  const float* B2   = (const float*)d_in[14];
  const float* lWih = (const float*)d_in[15];
  const float* lWhh = (const float*)d_in[16];
  const float* lBih = (const float*)d_in[17];
  const float* lBhh = (const float*)d_in[18];

  char* ws = (char*)d_ws;
  u16*  WihE = (u16*)(ws + oWihE);
  u16*  WhhE = (u16*)(ws + oWhhE);
  u16*  AttnW= (u16*)(ws + oAttnW);
  u16*  W1C  = (u16*)(ws + oW1C);
  u16*  W1O  = (u16*)(ws + oW1O);
  u16*  W2w  = (u16*)(ws + oW2);
  u16*  WihL = (u16*)(ws + oWihL);
  u16*  WhhL = (u16*)(ws + oWhhL);
  float* BEnc= (float*)(ws + oBEnc);
  float* BL  = (float*)(ws + oBL);
  u16*  DemoT= (u16*)(ws + oDemoT);
  u16*  ObsB = (u16*)(ws + oObsB);
  u16*  Xih  = (u16*)(ws + oXih);
  u16*  ObsP = (u16*)(ws + oObsP);
  u16*  DEnc = (u16*)(ws + oDEnc);
  u16*  APrj = (u16*)(ws + oAPrj);
  u16*  ZE   = (u16*)(ws + oZE);
  float* HFR = (float*)(ws + oHFR);
  u16*  HBR  = (u16*)(ws + oHBR);
  u16*  CtxR = (u16*)(ws + oCtxR);
  u16*  MBR  = (u16*)(ws + oMBR);
  u16*  XBR  = (u16*)(ws + oXBR);
  u32*  Bar  = (u32*)(ws + oBar);

  k_convert<<<1024, 256, 0, stream>>>(eWih, WihE, G4 * FF);
  k_convert<<<1024, 256, 0, stream>>>(eWhh, WhhE, G4 * HH);
  k_convert<<<512,  256, 0, stream>>>(aW,   AttnW, HH * HH);
  k_split_w1<<<1024, 256, 0, stream>>>(W1, W1C, W1O);
  k_convert<<<1024, 256, 0, stream>>>(W2,   W2w,  HH * G4);
  k_convert<<<1024, 256, 0, stream>>>(lWih, WihL, G4 * HH);
  k_convert<<<1024, 256, 0, stream>>>(lWhh, WhhL, G4 * HH);
  k_addb<<<16, 256, 0, stream>>>(eBih, eBhh, BEnc, G4);
  k_addb<<<16, 256, 0, stream>>>(lBih, lBhh, BL, G4);
  k_demo_t<<<1024, 256, 0, stream>>>(demo, DemoT);
  k_convert<<<512, 256, 0, stream>>>(obs, ObsB, TT * BB * FF);
  hipMemsetAsync(Bar, 0, 256, stream);

  {
    dim3 g(LL * BB / 128, G4 / 128);
    k_gemm_bt<0><<<g, 256, 0, stream>>>(DemoT, WihE, BEnc, Xih, LL * BB, G4, FF);
  }
  {
    dim3 g(TT * BB / 128, G4 / 128);
    k_gemm_bt<0><<<g, 256, 0, stream>>>(ObsB, W1O, B1, ObsP, TT * BB, G4, FF);
  }

  k_encoder<<<64, 256, 0, stream>>>(WhhE, Xih, ZE, DEnc, Bar);

  {
    dim3 g(LL * BB / 128, HH / 128);
    k_gemm_bt<0><<<g, 256, 0, stream>>>(DEnc, AttnW, aB, APrj, LL * BB, HH, HH);
  }

  k_decoder<<<64, 256, 0, stream>>>(APrj, DEnc, ObsP, W1C, W2w, WihL, WhhL,
                                    BL, B2, h0, c0, lens,
                                    HFR, HBR, CtxR, MBR, XBR, (float*)d_out, Bar + 16);
}